// Round 3
// baseline (757.933 us; speedup 1.0000x reference)
//
#include <hip/hip_runtime.h>
#include <hip/hip_bf16.h>
#include <stdint.h>

#define HID   2048
#define SLEN  2048
#define NB    2
#define NHEADS 32
#define NKVH   8
#define HDIM   64
#define KVW    512   // NKVH*HDIM

typedef __bf16 bf16_t;
typedef __bf16 bf16x8 __attribute__((ext_vector_type(8)));
typedef float  f32x4  __attribute__((ext_vector_type(4)));

#define NEG_BIG (-1.0e4f)   // masked-score sentinel: exp underflows to 0, no inf-inf paths

__device__ __forceinline__ f32x4 mfma16(bf16x8 a, bf16x8 b, f32x4 c) {
  return __builtin_amdgcn_mfma_f32_16x16x32_bf16(a, b, c, 0, 0, 0);
}

// Load 8 consecutive elements as bf16x8, converting if the source is fp32.
__device__ __forceinline__ bf16x8 ld8(const bf16_t* p) {
  return *(const bf16x8*)p;
}
__device__ __forceinline__ bf16x8 ld8(const float* p) {
  f32x4 a = *(const f32x4*)p;
  f32x4 b = *(const f32x4*)(p + 4);
  bf16x8 r;
  r[0] = (bf16_t)a[0]; r[1] = (bf16_t)a[1]; r[2] = (bf16_t)a[2]; r[3] = (bf16_t)a[3];
  r[4] = (bf16_t)b[0]; r[5] = (bf16_t)b[1]; r[6] = (bf16_t)b[2]; r[7] = (bf16_t)b[3];
  return r;
}

__device__ __forceinline__ void st_c(bf16_t* p, float v) { *p = (bf16_t)v; }
__device__ __forceinline__ void st_c(float*  p, float v) { *p = v; }

// One 128x128 tile of C = A * W^T + bias.  m92/m93 staging pattern
// (vector register load -> convert -> vector LDS store).
template <typename AT, typename CT>
__device__ __forceinline__ void gemm128_tile(
    const AT* __restrict__ Ap, int lda,
    const float* __restrict__ Wp, int ldw,
    const float* __restrict__ biasp,
    CT* __restrict__ Cp, int ldc,
    int K)
{
  __shared__ __align__(16) bf16_t Al[128 * 32];
  __shared__ __align__(16) bf16_t Bl[128 * 32];

  const int tid  = threadIdx.x;
  const int lane = tid & 63;
  const int w    = tid >> 6;
  const int fr   = lane & 15;
  const int quad = lane >> 4;
  const int wm   = (w >> 1) * 64;
  const int wn   = (w & 1) * 64;

  const f32x4 z4 = {0.f, 0.f, 0.f, 0.f};
  f32x4 acc[4][4];
  for (int i = 0; i < 4; ++i)
    for (int j = 0; j < 4; ++j) acc[i][j] = z4;

  const int c0    = w * 2;
  const int srow0 = lane >> 2;        // + c*16
  const int skc   = (lane & 3) * 8;

  for (int k0 = 0; k0 < K; k0 += 32) {
    bf16x8 av[2], bv[2];
    for (int t = 0; t < 2; ++t) {
      const int r = (c0 + t) * 16 + srow0;
      av[t] = ld8(Ap + (size_t)r * lda + k0 + skc);
      bv[t] = ld8(Wp + (size_t)r * ldw + k0 + skc);
    }
    for (int t = 0; t < 2; ++t) {
      const int c = c0 + t;
      *(bf16x8*)&Al[c * 512 + lane * 8] = av[t];
      *(bf16x8*)&Bl[c * 512 + lane * 8] = bv[t];
    }
    __syncthreads();
    bf16x8 af[4], bfr[4];
    for (int mi = 0; mi < 4; ++mi)
      af[mi] = *(const bf16x8*)&Al[(wm + mi * 16 + fr) * 32 + quad * 8];
    for (int ni = 0; ni < 4; ++ni)
      bfr[ni] = *(const bf16x8*)&Bl[(wn + ni * 16 + fr) * 32 + quad * 8];
    for (int mi = 0; mi < 4; ++mi)
      for (int ni = 0; ni < 4; ++ni)
        acc[mi][ni] = mfma16(af[mi], bfr[ni], acc[mi][ni]);
    __syncthreads();
  }

  // Epilogue: C/D layout is col=lane&15, row=quad*4+reg (m89/m91 verified).
  for (int ni = 0; ni < 4; ++ni) {
    const int col = wn + ni * 16 + fr;
    const float bz = biasp[col];
    for (int mi = 0; mi < 4; ++mi) {
      const int r0 = wm + mi * 16 + quad * 4;
      for (int r = 0; r < 4; ++r)
        st_c(Cp + (size_t)(r0 + r) * ldc + col, acc[mi][ni][r] + bz);
    }
  }
}

// x (fp32) * {Wq,Wk,Wv}(fp32)^T + b -> bf16 Q/K/V in workspace.
__global__ __launch_bounds__(256) void qkv_kernel(
    const float* __restrict__ x,
    const float* __restrict__ Wq, const float* __restrict__ bq,
    const float* __restrict__ Wk, const float* __restrict__ bk,
    const float* __restrict__ Wv, const float* __restrict__ bv,
    bf16_t* Qb, bf16_t* Kb, bf16_t* Vb)
{
  const int nb = blockIdx.x;   // 0..23: 16 Q blocks, 4 K blocks, 4 V blocks
  const int mb = blockIdx.y;   // 0..31
  const float* W; const float* bias; bf16_t* C; int ldc;
  if (nb < 16)      { W = Wq + (size_t)nb * 128 * HID;  bias = bq + nb * 128;
                      C = Qb + nb * 128; ldc = HID; }
  else if (nb < 20) { const int j = nb - 16;
                      W = Wk + (size_t)j * 128 * HID;   bias = bk + j * 128;
                      C = Kb + j * 128; ldc = KVW; }
  else              { const int j = nb - 20;
                      W = Wv + (size_t)j * 128 * HID;   bias = bv + j * 128;
                      C = Vb + j * 128; ldc = KVW; }
  gemm128_tile<float, bf16_t>(x + (size_t)mb * 128 * HID, HID, W, HID, bias,
                              C + (size_t)mb * 128 * ldc, ldc, HID);
}

// attn-out (bf16 ws) * Wo(fp32)^T + bo -> fp32 d_out.
__global__ __launch_bounds__(256) void oproj_kernel(
    const bf16_t* __restrict__ A, const float* __restrict__ Wo,
    const float* __restrict__ bo, float* out)
{
  const int nb = blockIdx.x, mb = blockIdx.y;
  gemm128_tile<bf16_t, float>(A + (size_t)mb * 128 * HID, HID,
                              Wo + (size_t)nb * 128 * HID, HID,
                              bo + nb * 128,
                              out + (size_t)mb * 128 * HID + nb * 128, HID, HID);
}

// Flash-style causal attention over bf16 ws buffers. Block = (b, h, 128-row q
// tile), 256 threads; wave w owns q rows [w*32, w*32+32).
__global__ __launch_bounds__(256) void attn_kernel(
    const bf16_t* __restrict__ Q, const bf16_t* __restrict__ Kg,
    const bf16_t* __restrict__ Vg, bf16_t* __restrict__ O)
{
  const int qt = blockIdx.x;
  const int h  = blockIdx.y;
  const int b  = blockIdx.z;
  const int kvh = h >> 2;            // GROUPS = 4

  const int tid  = threadIdx.x;
  const int lane = tid & 63;
  const int w    = tid >> 6;
  const int fr   = lane & 15;
  const int quad = lane >> 4;

  const int PS  = 136;   // P row stride (b128-aligned, benign banks)
  const int VTS = 136;   // V^T row stride
  __shared__ __align__(16) bf16_t KP[128 * 136];  // K-tile ([2][128][32]) aliased with P
  __shared__ __align__(16) bf16_t Vt[64 * 136];   // V^T tile

  const int q0 = qt * 128;
  const size_t qbase = (size_t)b * SLEN;

  // Q fragments (A-operand: m=lane&15, k=quad*8+j), kept in regs all loop.
  bf16x8 qf[2][2];
  for (int qi = 0; qi < 2; ++qi)
    for (int ks = 0; ks < 2; ++ks) {
      const size_t qrow = qbase + q0 + w * 32 + qi * 16 + fr;
      qf[qi][ks] = *(const bf16x8*)&Q[qrow * HID + h * HDIM + ks * 32 + quad * 8];
    }

  const f32x4 z4 = {0.f, 0.f, 0.f, 0.f};
  float m_i[2][4], l_i[2][4];
  f32x4 o_acc[2][4];
  for (int qi = 0; qi < 2; ++qi) {
    for (int r = 0; r < 4; ++r) { m_i[qi][r] = NEG_BIG; l_i[qi][r] = 0.f; }
    for (int di = 0; di < 4; ++di) o_acc[qi][di] = z4;
  }

  for (int kt = 0; kt <= qt; ++kt) {
    const size_t krow0 = qbase + kt * 128;

    // --- stage K tile as [half d][128 rows][32] ---
    for (int t = 0; t < 4; ++t) {
      const int c    = w * 4 + t;
      const int half = c >> 3;
      const int r    = (c & 7) * 16 + (lane >> 2);
      const int dk   = half * 32 + (lane & 3) * 8;
      bf16x8 kv = *(const bf16x8*)&Kg[(krow0 + r) * KVW + kvh * HDIM + dk];
      *(bf16x8*)&KP[c * 512 + lane * 8] = kv;
    }
    // --- stage V transposed: Vt[d][k] ---
    for (int t = 0; t < 4; ++t) {
      const int kk = t * 32 + (tid >> 3);
      const int d0 = (tid & 7) * 8;
      bf16x8 vv = *(const bf16x8*)&Vg[(krow0 + kk) * KVW + kvh * HDIM + d0];
      for (int j = 0; j < 8; ++j) Vt[(d0 + j) * VTS + kk] = vv[j];
    }
    __syncthreads();

    // --- S = Q K^T ---
    f32x4 s[2][8];
    for (int qi = 0; qi < 2; ++qi)
      for (int ki = 0; ki < 8; ++ki) s[qi][ki] = z4;
    for (int ks = 0; ks < 2; ++ks)
      for (int ki = 0; ki < 8; ++ki) {
        bf16x8 kf = *(const bf16x8*)&KP[ks * 4096 + (ki * 16 + fr) * 32 + quad * 8];
        s[0][ki] = mfma16(qf[0][ks], kf, s[0][ki]);
        s[1][ki] = mfma16(qf[1][ks], kf, s[1][ki]);
      }
    __syncthreads();   // all waves done reading K before P overwrites it

    // --- online softmax (scores in C-layout: col=fr=k, row=quad*4+r=q) ---
    const float sc = 0.125f;   // 1/sqrt(64)
    const bool diag = (kt == qt);
    float alpha[2][4];
    for (int qi = 0; qi < 2; ++qi) {
      for (int r = 0; r < 4; ++r) {
        float mx = NEG_BIG;
        for (int ki = 0; ki < 8; ++ki) {
          float v = s[qi][ki][r] * sc;
          if (diag) {
            const int kg_ = kt * 128 + ki * 16 + fr;
            const int qg_ = q0 + w * 32 + qi * 16 + quad * 4 + r;
            if (kg_ > qg_) v = NEG_BIG;
          }
          s[qi][ki][r] = v;
          mx = fmaxf(mx, v);
        }
        mx = fmaxf(mx, __shfl_xor(mx, 1));
        mx = fmaxf(mx, __shfl_xor(mx, 2));
        mx = fmaxf(mx, __shfl_xor(mx, 4));
        mx = fmaxf(mx, __shfl_xor(mx, 8));
        const float mn = fmaxf(m_i[qi][r], mx);
        alpha[qi][r] = __expf(m_i[qi][r] - mn);
        m_i[qi][r] = mn;
        float rs = 0.f;
        for (int ki = 0; ki < 8; ++ki) {
          const float p = __expf(s[qi][ki][r] - mn);
          s[qi][ki][r] = p;
          rs += p;
        }
        rs += __shfl_xor(rs, 1);
        rs += __shfl_xor(rs, 2);
        rs += __shfl_xor(rs, 4);
        rs += __shfl_xor(rs, 8);
        l_i[qi][r] = l_i[qi][r] * alpha[qi][r] + rs;
      }
      for (int di = 0; di < 4; ++di)
        for (int r = 0; r < 4; ++r)
          o_acc[qi][di][r] *= alpha[qi][r];
    }

    // --- P: C-layout regs -> LDS (row-major [q][k], bf16) ---
    for (int qi = 0; qi < 2; ++qi)
      for (int ki = 0; ki < 8; ++ki)
        for (int r = 0; r < 4; ++r)
          KP[(w * 32 + qi * 16 + quad * 4 + r) * PS + ki * 16 + fr] =
              (bf16_t)s[qi][ki][r];
    __syncthreads();

    // --- O += P V ---
    for (int ks2 = 0; ks2 < 4; ++ks2) {
      bf16x8 pf0 = *(const bf16x8*)&KP[(w * 32 + fr) * PS + ks2 * 32 + quad * 8];
      bf16x8 pf1 = *(const bf16x8*)&KP[(w * 32 + 16 + fr) * PS + ks2 * 32 + quad * 8];
      for (int di = 0; di < 4; ++di) {
        bf16x8 vf = *(const bf16x8*)&Vt[(di * 16 + fr) * VTS + ks2 * 32 + quad * 8];
        o_acc[0][di] = mfma16(pf0, vf, o_acc[0][di]);
        o_acc[1][di] = mfma16(pf1, vf, o_acc[1][di]);
      }
    }
    __syncthreads();   // KP/Vt free for next k-tile staging
  }

  // --- epilogue: O / l ---
  for (int qi = 0; qi < 2; ++qi)
    for (int r = 0; r < 4; ++r) {
      const float rl = 1.f / fmaxf(l_i[qi][r], 1e-20f);
      const size_t qg_ = qbase + q0 + w * 32 + qi * 16 + quad * 4 + r;
      for (int di = 0; di < 4; ++di)
        O[qg_ * HID + h * HDIM + di * 16 + fr] = (bf16_t)(o_acc[qi][di][r] * rl);
    }
}

extern "C" void kernel_launch(void* const* d_in, const int* in_sizes, int n_in,
                              void* d_out, int out_size, void* d_ws, size_t ws_size,
                              hipStream_t stream) {
  // Reference dtypes: all float32 (mask int32). Output float32.
  const float* x  = (const float*)d_in[0];
  // d_in[1] = causal mask (int32) -- recomputed inline, not read
  const float* Wq = (const float*)d_in[2];
  const float* bq = (const float*)d_in[3];
  const float* Wk = (const float*)d_in[4];
  const float* bk = (const float*)d_in[5];
  const float* Wv = (const float*)d_in[6];
  const float* bv = (const float*)d_in[7];
  const float* Wo = (const float*)d_in[8];
  const float* bo = (const float*)d_in[9];
  float* out = (float*)d_out;

  const size_t M = (size_t)NB * SLEN;          // 4096
  bf16_t* Qb = (bf16_t*)d_ws;                  // 4096 x 2048 (bf16)
  bf16_t* Kb = Qb + M * HID;                   // 4096 x 512
  bf16_t* Vb = Kb + M * KVW;                   // 4096 x 512
  bf16_t* Ab = Vb + M * KVW;                   // 4096 x 2048

  dim3 blk(256, 1, 1);
  qkv_kernel<<<dim3(24, 32, 1), blk, 0, stream>>>(x, Wq, bq, Wk, bk, Wv, bv, Qb, Kb, Vb);
  attn_kernel<<<dim3(16, 32, 2), blk, 0, stream>>>(Qb, Kb, Vb, Ab);
  oproj_kernel<<<dim3(16, 32, 1), blk, 0, stream>>>(Ab, Wo, bo, out);
}

// Round 4
// 371.663 us; speedup vs baseline: 2.0393x; 2.0393x over previous
//
#include <hip/hip_runtime.h>
#include <hip/hip_bf16.h>
#include <stdint.h>

#define HID   2048
#define SLEN  2048
#define NB    2
#define NHEADS 32
#define NKVH   8
#define HDIM   64
#define KVW    512   // NKVH*HDIM

typedef __bf16 bf16_t;
typedef __bf16 bf16x8 __attribute__((ext_vector_type(8)));
typedef float  f32x4  __attribute__((ext_vector_type(4)));

__device__ __forceinline__ f32x4 mfma16(bf16x8 a, bf16x8 b, f32x4 c) {
  return __builtin_amdgcn_mfma_f32_16x16x32_bf16(a, b, c, 0, 0, 0);
}

__device__ __forceinline__ void gl2lds16(const bf16_t* g, bf16_t* l) {
  __builtin_amdgcn_global_load_lds(
      (const __attribute__((address_space(1))) void*)g,
      (__attribute__((address_space(3))) void*)l,
      16, 0, 0);
}

__device__ __forceinline__ float fast_exp2(float x) {
#if __has_builtin(__builtin_amdgcn_exp2f)
  return __builtin_amdgcn_exp2f(x);
#else
  return __expf(x * 0.69314718f);   // e^(x ln2) = 2^x
#endif
}

// Load 8 consecutive elements as bf16x8, converting if the source is fp32.
__device__ __forceinline__ bf16x8 ld8(const bf16_t* p) {
  return *(const bf16x8*)p;
}
__device__ __forceinline__ bf16x8 ld8(const float* p) {
  f32x4 a = *(const f32x4*)p;
  f32x4 b = *(const f32x4*)(p + 4);
  bf16x8 r;
  r[0] = (bf16_t)a[0]; r[1] = (bf16_t)a[1]; r[2] = (bf16_t)a[2]; r[3] = (bf16_t)a[3];
  r[4] = (bf16_t)b[0]; r[5] = (bf16_t)b[1]; r[6] = (bf16_t)b[2]; r[7] = (bf16_t)b[3];
  return r;
}

__device__ __forceinline__ void st_c(bf16_t* p, float v) { *p = (bf16_t)v; }
__device__ __forceinline__ void st_c(float*  p, float v) { *p = v; }

// ---------------- GEMM (unchanged from the passing Round-3 kernel) ----------
template <typename AT, typename CT>
__device__ __forceinline__ void gemm128_tile(
    const AT* __restrict__ Ap, int lda,
    const float* __restrict__ Wp, int ldw,
    const float* __restrict__ biasp,
    CT* __restrict__ Cp, int ldc,
    int K)
{
  __shared__ __align__(16) bf16_t Al[128 * 32];
  __shared__ __align__(16) bf16_t Bl[128 * 32];

  const int tid  = threadIdx.x;
  const int lane = tid & 63;
  const int w    = tid >> 6;
  const int fr   = lane & 15;
  const int quad = lane >> 4;
  const int wm   = (w >> 1) * 64;
  const int wn   = (w & 1) * 64;

  const f32x4 z4 = {0.f, 0.f, 0.f, 0.f};
  f32x4 acc[4][4];
  for (int i = 0; i < 4; ++i)
    for (int j = 0; j < 4; ++j) acc[i][j] = z4;

  const int c0    = w * 2;
  const int srow0 = lane >> 2;
  const int skc   = (lane & 3) * 8;

  for (int k0 = 0; k0 < K; k0 += 32) {
    bf16x8 av[2], bv[2];
    for (int t = 0; t < 2; ++t) {
      const int r = (c0 + t) * 16 + srow0;
      av[t] = ld8(Ap + (size_t)r * lda + k0 + skc);
      bv[t] = ld8(Wp + (size_t)r * ldw + k0 + skc);
    }
    for (int t = 0; t < 2; ++t) {
      const int c = c0 + t;
      *(bf16x8*)&Al[c * 512 + lane * 8] = av[t];
      *(bf16x8*)&Bl[c * 512 + lane * 8] = bv[t];
    }
    __syncthreads();
    bf16x8 af[4], bfr[4];
    for (int mi = 0; mi < 4; ++mi)
      af[mi] = *(const bf16x8*)&Al[(wm + mi * 16 + fr) * 32 + quad * 8];
    for (int ni = 0; ni < 4; ++ni)
      bfr[ni] = *(const bf16x8*)&Bl[(wn + ni * 16 + fr) * 32 + quad * 8];
    for (int mi = 0; mi < 4; ++mi)
      for (int ni = 0; ni < 4; ++ni)
        acc[mi][ni] = mfma16(af[mi], bfr[ni], acc[mi][ni]);
    __syncthreads();
  }

  for (int ni = 0; ni < 4; ++ni) {
    const int col = wn + ni * 16 + fr;
    const float bz = biasp[col];
    for (int mi = 0; mi < 4; ++mi) {
      const int r0 = wm + mi * 16 + quad * 4;
      for (int r = 0; r < 4; ++r)
        st_c(Cp + (size_t)(r0 + r) * ldc + col, acc[mi][ni][r] + bz);
    }
  }
}

__global__ __launch_bounds__(256) void qkv_kernel(
    const float* __restrict__ x,
    const float* __restrict__ Wq, const float* __restrict__ bq,
    const float* __restrict__ Wk, const float* __restrict__ bk,
    const float* __restrict__ Wv, const float* __restrict__ bv,
    bf16_t* Qb, bf16_t* Kb, bf16_t* Vb)
{
  const int nb = blockIdx.x;
  const int mb = blockIdx.y;
  const float* W; const float* bias; bf16_t* C; int ldc;
  if (nb < 16)      { W = Wq + (size_t)nb * 128 * HID;  bias = bq + nb * 128;
                      C = Qb + nb * 128; ldc = HID; }
  else if (nb < 20) { const int j = nb - 16;
                      W = Wk + (size_t)j * 128 * HID;   bias = bk + j * 128;
                      C = Kb + j * 128; ldc = KVW; }
  else              { const int j = nb - 20;
                      W = Wv + (size_t)j * 128 * HID;   bias = bv + j * 128;
                      C = Vb + j * 128; ldc = KVW; }
  gemm128_tile<float, bf16_t>(x + (size_t)mb * 128 * HID, HID, W, HID, bias,
                              C + (size_t)mb * 128 * ldc, ldc, HID);
}

__global__ __launch_bounds__(256) void oproj_kernel(
    const bf16_t* __restrict__ A, const float* __restrict__ Wo,
    const float* __restrict__ bo, float* out)
{
  const int nb = blockIdx.x, mb = blockIdx.y;
  gemm128_tile<bf16_t, float>(A + (size_t)mb * 128 * HID, HID,
                              Wo + (size_t)nb * 128 * HID, HID,
                              bo + nb * 128,
                              out + (size_t)mb * 128 * HID + nb * 128, HID, HID);
}

// ---------------- V pre-transpose: Vb[s][kvh*64+d] -> VbT[b][kvh][d][s] -----
__global__ __launch_bounds__(256) void vtrans_kernel(
    const bf16_t* __restrict__ Vb, bf16_t* __restrict__ VbT)
{
  __shared__ bf16_t T[64][72];
  const int st = blockIdx.x, kvh = blockIdx.y, b = blockIdx.z;
  const int tid = threadIdx.x;
  {
    const int row = tid >> 2;          // s within tile
    const int c16 = (tid & 3) * 16;    // d offset
    const bf16_t* src =
        Vb + ((size_t)b * SLEN + st * 64 + row) * KVW + kvh * HDIM + c16;
    *(bf16x8*)&T[row][c16]     = *(const bf16x8*)(src);
    *(bf16x8*)&T[row][c16 + 8] = *(const bf16x8*)(src + 8);
  }
  __syncthreads();
  {
    const int d  = tid >> 2;
    const int sc = (tid & 3) * 16;
    bf16_t tmp[16];
    for (int j = 0; j < 16; ++j) tmp[j] = T[sc + j][d];
    bf16_t* dst = VbT + ((size_t)(b * NKVH + kvh) * HDIM + d) * SLEN + st * 64 + sc;
    *(bf16x8*)dst       = *(bf16x8*)&tmp[0];
    *(bf16x8*)(dst + 8) = *(bf16x8*)&tmp[8];
  }
}

// ---------------- Flash attention, paired q-tiles, fixed-base softmax -------
// Block = (pid, h, b) handles q-tiles {pid, 15-pid}: 17 tile-iters every block.
// O written in-place over Q (disjoint row x h-slice per block, read-before-write).
__global__ __launch_bounds__(256) void attn_kernel(
    const bf16_t* Q, const bf16_t* __restrict__ Kg,
    const bf16_t* __restrict__ VT, bf16_t* O)
{
  const int pid = blockIdx.x;        // 0..7
  const int h   = blockIdx.y;
  const int b   = blockIdx.z;
  const int kvh = h >> 2;

  const int tid  = threadIdx.x;
  const int lane = tid & 63;
  const int w    = tid >> 6;
  const int fr   = lane & 15;
  const int quad = lane >> 4;

  const int PS  = 72;    // P half-k row stride (144 B, 16B-aligned)
  const int VTS = 136;   // V^T row stride
  __shared__ __align__(16) bf16_t KL[8192];        // K tile [2][128][32], 16 KB
  __shared__ __align__(16) bf16_t PP[128 * 72];    // P half-k, per-wave rows, 18 KB
  __shared__ __align__(16) bf16_t Vt[64 * 136];    // V^T tile, 17 KB

  const size_t qbase = (size_t)b * SLEN;
  const bf16_t* VTh = VT + (size_t)(b * NKVH + kvh) * HDIM * SLEN;

  // ones B-fragment: B[k][0]=1 -> column 0 of the PV accumulator = row-sum l.
  bf16x8 ones8;
  {
    const bf16_t o1 = (bf16_t)(fr == 0 ? 1.0f : 0.0f);
    for (int j = 0; j < 8; ++j) ones8[j] = o1;
  }

  for (int half = 0; half < 2; ++half) {
    const int qt = half ? (15 - pid) : pid;
    const int q0 = qt * 128;

    bf16x8 qf[2][2];
    for (int qi = 0; qi < 2; ++qi)
      for (int ks = 0; ks < 2; ++ks) {
        const size_t qrow = qbase + q0 + w * 32 + qi * 16 + fr;
        qf[qi][ks] = *(const bf16x8*)&Q[qrow * HID + h * HDIM + ks * 32 + quad * 8];
      }

    const f32x4 z4 = {0.f, 0.f, 0.f, 0.f};
    f32x4 o_acc[2][4];
    f32x4 o_l[2];
    for (int qi = 0; qi < 2; ++qi) {
      o_l[qi] = z4;
      for (int di = 0; di < 4; ++di) o_acc[qi][di] = z4;
    }

    for (int kt = 0; kt <= qt; ++kt) {
      const size_t krow0 = qbase + kt * 128;

      // --- K tile -> LDS via async DMA, layout [hf][row][32] ---
      for (int t = 0; t < 4; ++t) {
        const int c  = w * 4 + t;
        const int hf = c >> 3;
        const int r  = (c & 7) * 16 + (lane >> 2);
        const int dk = hf * 32 + (lane & 3) * 8;
        gl2lds16(&Kg[(krow0 + r) * KVW + kvh * HDIM + dk], &KL[c * 512 + lane * 8]);
      }
      // --- V^T tile (pre-transposed) -> LDS, pure vector copies ---
      {
        const int d  = tid >> 2;
        const int kc = (tid & 3) * 32;
        const bf16_t* src = VTh + (size_t)d * SLEN + kt * 128 + kc;
        bf16x8 v0 = *(const bf16x8*)(src);
        bf16x8 v1 = *(const bf16x8*)(src + 8);
        bf16x8 v2 = *(const bf16x8*)(src + 16);
        bf16x8 v3 = *(const bf16x8*)(src + 24);
        bf16_t* dst = &Vt[d * VTS + kc];
        *(bf16x8*)(dst)      = v0;
        *(bf16x8*)(dst + 8)  = v1;
        *(bf16x8*)(dst + 16) = v2;
        *(bf16x8*)(dst + 24) = v3;
      }
      __syncthreads();

      // --- S = Q K^T ---
      f32x4 s[2][8];
      for (int qi = 0; qi < 2; ++qi)
        for (int ki = 0; ki < 8; ++ki) s[qi][ki] = z4;
      for (int ks = 0; ks < 2; ++ks)
        for (int ki = 0; ki < 8; ++ki) {
          bf16x8 kf = *(const bf16x8*)&KL[ks * 4096 + (ki * 16 + fr) * 32 + quad * 8];
          s[0][ki] = mfma16(qf[0][ks], kf, s[0][ki]);
          s[1][ki] = mfma16(qf[1][ks], kf, s[1][ki]);
        }

      // --- P = exp2(S * log2e/sqrt(D)); causal zeroing on diag tile only.
      // Scores are bounded (|S|/8 <~ 20) so fixed-base exp is fp32-safe;
      // l accumulates via the ones-MFMA below. P rows are wave-private ->
      // no barrier needed (per-wave in-order LDS).
      const float C2 = 0.18033688f;   // log2(e)/8
      const bool diag = (kt == qt);
      for (int hk = 0; hk < 2; ++hk) {
        for (int qi = 0; qi < 2; ++qi)
          for (int k2 = 0; k2 < 4; ++k2) {
            const int ki = hk * 4 + k2;
            for (int r = 0; r < 4; ++r) {
              float pe = fast_exp2(s[qi][ki][r] * C2);
              if (diag && (ki * 16 + fr > w * 32 + qi * 16 + quad * 4 + r))
                pe = 0.f;
              PP[(w * 32 + qi * 16 + quad * 4 + r) * PS + k2 * 16 + fr] =
                  (bf16_t)pe;
            }
          }
        // --- O += P V (this k-half), l += P . 1 ---
        for (int k2 = 0; k2 < 2; ++k2) {
          bf16x8 pf0 = *(const bf16x8*)&PP[(w * 32 + fr) * PS + k2 * 32 + quad * 8];
          bf16x8 pf1 = *(const bf16x8*)&PP[(w * 32 + 16 + fr) * PS + k2 * 32 + quad * 8];
          o_l[0] = mfma16(pf0, ones8, o_l[0]);
          o_l[1] = mfma16(pf1, ones8, o_l[1]);
          const int kb = hk * 64 + k2 * 32;
          for (int di = 0; di < 4; ++di) {
            bf16x8 vf = *(const bf16x8*)&Vt[(di * 16 + fr) * VTS + kb + quad * 8];
            o_acc[0][di] = mfma16(pf0, vf, o_acc[0][di]);
            o_acc[1][di] = mfma16(pf1, vf, o_acc[1][di]);
          }
        }
      }
      __syncthreads();   // KL/Vt free for next k-tile staging
    }

    // --- epilogue: O / l ; l lives in C/D column 0 (lane quad*16, reg r) ---
    for (int qi = 0; qi < 2; ++qi)
      for (int r = 0; r < 4; ++r) {
        const float l  = __shfl(o_l[qi][r], lane & 48);
        const float rl = 1.f / l;
        const size_t qg_ = qbase + q0 + w * 32 + qi * 16 + quad * 4 + r;
        for (int di = 0; di < 4; ++di)
          O[qg_ * HID + h * HDIM + di * 16 + fr] = (bf16_t)(o_acc[qi][di][r] * rl);
      }
  }
}

extern "C" void kernel_launch(void* const* d_in, const int* in_sizes, int n_in,
                              void* d_out, int out_size, void* d_ws, size_t ws_size,
                              hipStream_t stream) {
  const float* x  = (const float*)d_in[0];
  // d_in[1] = causal mask (int32) -- recomputed inline, not read
  const float* Wq = (const float*)d_in[2];
  const float* bq = (const float*)d_in[3];
  const float* Wk = (const float*)d_in[4];
  const float* bk = (const float*)d_in[5];
  const float* Wv = (const float*)d_in[6];
  const float* bv = (const float*)d_in[7];
  const float* Wo = (const float*)d_in[8];
  const float* bo = (const float*)d_in[9];
  float* out = (float*)d_out;

  const size_t M = (size_t)NB * SLEN;          // 4096
  bf16_t* Qb  = (bf16_t*)d_ws;                 // 4096 x 2048 (Q, then attn-out in-place)
  bf16_t* Kb  = Qb + M * HID;                  // 4096 x 512
  bf16_t* Vb  = Kb + M * KVW;                  // 4096 x 512
  bf16_t* VbT = Vb + M * KVW;                  // [2][8][64][2048]

  dim3 blk(256, 1, 1);
  qkv_kernel<<<dim3(24, 32, 1), blk, 0, stream>>>(x, Wq, bq, Wk, bk, Wv, bv, Qb, Kb, Vb);
  vtrans_kernel<<<dim3(32, 8, 2), blk, 0, stream>>>(Vb, VbT);
  attn_kernel<<<dim3(8, 32, 2), blk, 0, stream>>>(Qb, Kb, VbT, Qb);
  oproj_kernel<<<dim3(16, 32, 1), blk, 0, stream>>>(Qb, Wo, bo, out);
}

// Round 5
// 337.865 us; speedup vs baseline: 2.2433x; 1.1000x over previous
//
#include <hip/hip_runtime.h>
#include <hip/hip_bf16.h>
#include <stdint.h>

#define HID   2048
#define SLEN  2048
#define NB    2
#define NHEADS 32
#define NKVH   8
#define HDIM   64
#define KVW    512   // NKVH*HDIM

typedef __bf16 bf16_t;
typedef __bf16 bf16x4 __attribute__((ext_vector_type(4)));
typedef __bf16 bf16x8 __attribute__((ext_vector_type(8)));
typedef float  f32x4  __attribute__((ext_vector_type(4)));

__device__ __forceinline__ f32x4 mfma16(bf16x8 a, bf16x8 b, f32x4 c) {
  return __builtin_amdgcn_mfma_f32_16x16x32_bf16(a, b, c, 0, 0, 0);
}

__device__ __forceinline__ void gl2lds16(const bf16_t* g, bf16_t* l) {
  __builtin_amdgcn_global_load_lds(
      (const __attribute__((address_space(1))) void*)g,
      (__attribute__((address_space(3))) void*)l,
      16, 0, 0);
}

__device__ __forceinline__ float fast_exp2(float x) {
#if __has_builtin(__builtin_amdgcn_exp2f)
  return __builtin_amdgcn_exp2f(x);
#else
  return __expf(x * 0.69314718f);
#endif
}

__device__ __forceinline__ bf16x8 ld8(const bf16_t* p) {
  return *(const bf16x8*)p;
}
__device__ __forceinline__ bf16x8 ld8(const float* p) {
  f32x4 a = *(const f32x4*)p;
  f32x4 b = *(const f32x4*)(p + 4);
  bf16x8 r;
  r[0] = (bf16_t)a[0]; r[1] = (bf16_t)a[1]; r[2] = (bf16_t)a[2]; r[3] = (bf16_t)a[3];
  r[4] = (bf16_t)b[0]; r[5] = (bf16_t)b[1]; r[6] = (bf16_t)b[2]; r[7] = (bf16_t)b[3];
  return r;
}

__device__ __forceinline__ void st_c(bf16_t* p, float v) { *p = (bf16_t)v; }
__device__ __forceinline__ void st_c(float*  p, float v) { *p = v; }

// ---------------- fp32 -> bf16 convert pass (Path A prologue) ---------------
__global__ __launch_bounds__(256) void cvt_kernel(
    const float* __restrict__ x,  const float* __restrict__ wq,
    const float* __restrict__ wk, const float* __restrict__ wv,
    const float* __restrict__ wo,
    bf16_t* xb, bf16_t* wqb, bf16_t* wkb, bf16_t* wvb, bf16_t* wob)
{
  const float* s; bf16_t* d; size_t n;
  switch (blockIdx.y) {
    case 0:  s = x;  d = xb;  n = (size_t)NB * SLEN * HID; break;
    case 1:  s = wq; d = wqb; n = (size_t)HID * HID; break;
    case 2:  s = wk; d = wkb; n = (size_t)KVW * HID; break;
    case 3:  s = wv; d = wvb; n = (size_t)KVW * HID; break;
    default: s = wo; d = wob; n = (size_t)HID * HID; break;
  }
  const size_t stride = (size_t)gridDim.x * 256 * 8;
  for (size_t i = ((size_t)blockIdx.x * 256 + threadIdx.x) * 8; i < n; i += stride)
    *(bf16x8*)(d + i) = ld8(s + i);
}

// ---------------- m97-style pure-bf16 GEMM tile (DMA staging) ---------------
// C = A * W^T + bias over a 128x128 tile, K-loop of 32.
// TRANSV: store C transposed (Cp[col*ldc + row], bf16x4-packed) for VbT.
template <typename CT, bool TRANSV>
__device__ __forceinline__ void gemm128_dma(
    const bf16_t* __restrict__ Ap, int lda,
    const bf16_t* __restrict__ Wp, int ldw,
    const float* __restrict__ biasp,
    CT* __restrict__ Cp, int ldc, int K)
{
  __shared__ __align__(16) bf16_t Al[128 * 32];
  __shared__ __align__(16) bf16_t Bl[128 * 32];

  const int tid  = threadIdx.x;
  const int lane = tid & 63;
  const int w    = tid >> 6;
  const int fr   = lane & 15;
  const int quad = lane >> 4;
  const int wm   = (w >> 1) * 64;
  const int wn   = (w & 1) * 64;

  const f32x4 z4 = {0.f, 0.f, 0.f, 0.f};
  f32x4 acc[4][4];
  for (int i = 0; i < 4; ++i)
    for (int j = 0; j < 4; ++j) acc[i][j] = z4;

  const int c0    = w * 2;
  const int srow0 = lane >> 2;        // + c*16
  const int skc   = (lane & 3) * 8;

  for (int k0 = 0; k0 < K; k0 += 32) {
    for (int t = 0; t < 2; ++t) {
      const int c = c0 + t;
      const int r = c * 16 + srow0;
      gl2lds16(Ap + (size_t)r * lda + k0 + skc, &Al[c * 512 + lane * 8]);
      gl2lds16(Wp + (size_t)r * ldw + k0 + skc, &Bl[c * 512 + lane * 8]);
    }
    __syncthreads();   // drains vmcnt (compiler emits waitcnt before barrier)
    bf16x8 af[4], bfr[4];
    for (int mi = 0; mi < 4; ++mi)
      af[mi] = *(const bf16x8*)&Al[(wm + mi * 16 + fr) * 32 + quad * 8];
    for (int ni = 0; ni < 4; ++ni)
      bfr[ni] = *(const bf16x8*)&Bl[(wn + ni * 16 + fr) * 32 + quad * 8];
    for (int mi = 0; mi < 4; ++mi)
      for (int ni = 0; ni < 4; ++ni)
        acc[mi][ni] = mfma16(af[mi], bfr[ni], acc[mi][ni]);
    __syncthreads();
  }

  // Epilogue: C/D layout col=lane&15, row=quad*4+reg (m89/m91 verified).
  for (int ni = 0; ni < 4; ++ni) {
    const int col = wn + ni * 16 + fr;
    const float bz = biasp[col];
    for (int mi = 0; mi < 4; ++mi) {
      const int r0 = wm + mi * 16 + quad * 4;
      if constexpr (TRANSV) {
        bf16x4 pk;
        for (int r = 0; r < 4; ++r) pk[r] = (bf16_t)(acc[mi][ni][r] + bz);
        *(bf16x4*)&Cp[(size_t)col * ldc + r0] = pk;
      } else {
        for (int r = 0; r < 4; ++r)
          st_c(Cp + (size_t)(r0 + r) * ldc + col, acc[mi][ni][r] + bz);
      }
    }
  }
}

// Path A QKV: pure-bf16 inputs; V written directly transposed into VbT.
__global__ __launch_bounds__(256) void qkv_dma_kernel(
    const bf16_t* __restrict__ xb,
    const bf16_t* __restrict__ Wqb, const float* __restrict__ bq,
    const bf16_t* __restrict__ Wkb, const float* __restrict__ bk,
    const bf16_t* __restrict__ Wvb, const float* __restrict__ bv,
    bf16_t* Qb, bf16_t* Kb, bf16_t* VbT)
{
  const int nb = blockIdx.x;   // 16 Q, 4 K, 4 V
  const int mb = blockIdx.y;   // 32
  const bf16_t* A = xb + (size_t)mb * 128 * HID;
  if (nb < 16) {
    gemm128_dma<bf16_t, false>(A, HID, Wqb + (size_t)nb * 128 * HID, HID,
                               bq + nb * 128,
                               Qb + (size_t)mb * 128 * HID + nb * 128, HID, HID);
  } else if (nb < 20) {
    const int j = nb - 16;
    gemm128_dma<bf16_t, false>(A, HID, Wkb + (size_t)j * 128 * HID, HID,
                               bk + j * 128,
                               Kb + (size_t)mb * 128 * KVW + j * 128, KVW, HID);
  } else {
    const int j = nb - 20;        // V block: cols j*128.. = kvh {2j, 2j+1}
    const int b = mb >> 4;        // batch; s_in_b = (mb&15)*128 + local row
    // VbT[b][kvh][d][s]: (kvh_local*64 + d) == local col -> col*SLEN + s.
    bf16_t* Cv = VbT + ((size_t)(b * NKVH + j * 2) * HDIM) * SLEN + (mb & 15) * 128;
    gemm128_dma<bf16_t, true>(A, HID, Wvb + (size_t)j * 128 * HID, HID,
                              bv + j * 128, Cv, SLEN, HID);
  }
}

__global__ __launch_bounds__(256) void oproj_dma_kernel(
    const bf16_t* __restrict__ A, const bf16_t* __restrict__ Wob,
    const float* __restrict__ bo, float* out)
{
  const int nb = blockIdx.x, mb = blockIdx.y;
  gemm128_dma<float, false>(A + (size_t)mb * 128 * HID, HID,
                            Wob + (size_t)nb * 128 * HID, HID,
                            bo + nb * 128,
                            out + (size_t)mb * 128 * HID + nb * 128, HID, HID);
}

// ---------------- Path B (fallback, Round-4 verbatim): fp32-source GEMM -----
template <typename AT, typename CT>
__device__ __forceinline__ void gemm128_tile(
    const AT* __restrict__ Ap, int lda,
    const float* __restrict__ Wp, int ldw,
    const float* __restrict__ biasp,
    CT* __restrict__ Cp, int ldc,
    int K)
{
  __shared__ __align__(16) bf16_t Al[128 * 32];
  __shared__ __align__(16) bf16_t Bl[128 * 32];

  const int tid  = threadIdx.x;
  const int lane = tid & 63;
  const int w    = tid >> 6;
  const int fr   = lane & 15;
  const int quad = lane >> 4;
  const int wm   = (w >> 1) * 64;
  const int wn   = (w & 1) * 64;

  const f32x4 z4 = {0.f, 0.f, 0.f, 0.f};
  f32x4 acc[4][4];
  for (int i = 0; i < 4; ++i)
    for (int j = 0; j < 4; ++j) acc[i][j] = z4;

  const int c0    = w * 2;
  const int srow0 = lane >> 2;
  const int skc   = (lane & 3) * 8;

  for (int k0 = 0; k0 < K; k0 += 32) {
    bf16x8 av[2], bv[2];
    for (int t = 0; t < 2; ++t) {
      const int r = (c0 + t) * 16 + srow0;
      av[t] = ld8(Ap + (size_t)r * lda + k0 + skc);
      bv[t] = ld8(Wp + (size_t)r * ldw + k0 + skc);
    }
    for (int t = 0; t < 2; ++t) {
      const int c = c0 + t;
      *(bf16x8*)&Al[c * 512 + lane * 8] = av[t];
      *(bf16x8*)&Bl[c * 512 + lane * 8] = bv[t];
    }
    __syncthreads();
    bf16x8 af[4], bfr[4];
    for (int mi = 0; mi < 4; ++mi)
      af[mi] = *(const bf16x8*)&Al[(wm + mi * 16 + fr) * 32 + quad * 8];
    for (int ni = 0; ni < 4; ++ni)
      bfr[ni] = *(const bf16x8*)&Bl[(wn + ni * 16 + fr) * 32 + quad * 8];
    for (int mi = 0; mi < 4; ++mi)
      for (int ni = 0; ni < 4; ++ni)
        acc[mi][ni] = mfma16(af[mi], bfr[ni], acc[mi][ni]);
    __syncthreads();
  }

  for (int ni = 0; ni < 4; ++ni) {
    const int col = wn + ni * 16 + fr;
    const float bz = biasp[col];
    for (int mi = 0; mi < 4; ++mi) {
      const int r0 = wm + mi * 16 + quad * 4;
      for (int r = 0; r < 4; ++r)
        st_c(Cp + (size_t)(r0 + r) * ldc + col, acc[mi][ni][r] + bz);
    }
  }
}

__global__ __launch_bounds__(256) void qkv_kernel(
    const float* __restrict__ x,
    const float* __restrict__ Wq, const float* __restrict__ bq,
    const float* __restrict__ Wk, const float* __restrict__ bk,
    const float* __restrict__ Wv, const float* __restrict__ bv,
    bf16_t* Qb, bf16_t* Kb, bf16_t* Vb)
{
  const int nb = blockIdx.x;
  const int mb = blockIdx.y;
  const float* W; const float* bias; bf16_t* C; int ldc;
  if (nb < 16)      { W = Wq + (size_t)nb * 128 * HID;  bias = bq + nb * 128;
                      C = Qb + nb * 128; ldc = HID; }
  else if (nb < 20) { const int j = nb - 16;
                      W = Wk + (size_t)j * 128 * HID;   bias = bk + j * 128;
                      C = Kb + j * 128; ldc = KVW; }
  else              { const int j = nb - 20;
                      W = Wv + (size_t)j * 128 * HID;   bias = bv + j * 128;
                      C = Vb + j * 128; ldc = KVW; }
  gemm128_tile<float, bf16_t>(x + (size_t)mb * 128 * HID, HID, W, HID, bias,
                              C + (size_t)mb * 128 * ldc, ldc, HID);
}

__global__ __launch_bounds__(256) void oproj_kernel(
    const bf16_t* __restrict__ A, const float* __restrict__ Wo,
    const float* __restrict__ bo, float* out)
{
  const int nb = blockIdx.x, mb = blockIdx.y;
  gemm128_tile<bf16_t, float>(A + (size_t)mb * 128 * HID, HID,
                              Wo + (size_t)nb * 128 * HID, HID,
                              bo + nb * 128,
                              out + (size_t)mb * 128 * HID + nb * 128, HID, HID);
}

__global__ __launch_bounds__(256) void vtrans_kernel(
    const bf16_t* __restrict__ Vb, bf16_t* __restrict__ VbT)
{
  __shared__ bf16_t T[64][72];
  const int st = blockIdx.x, kvh = blockIdx.y, b = blockIdx.z;
  const int tid = threadIdx.x;
  {
    const int row = tid >> 2;
    const int c16 = (tid & 3) * 16;
    const bf16_t* src =
        Vb + ((size_t)b * SLEN + st * 64 + row) * KVW + kvh * HDIM + c16;
    *(bf16x8*)&T[row][c16]     = *(const bf16x8*)(src);
    *(bf16x8*)&T[row][c16 + 8] = *(const bf16x8*)(src + 8);
  }
  __syncthreads();
  {
    const int d  = tid >> 2;
    const int sc = (tid & 3) * 16;
    bf16_t tmp[16];
    for (int j = 0; j < 16; ++j) tmp[j] = T[sc + j][d];
    bf16_t* dst = VbT + ((size_t)(b * NKVH + kvh) * HDIM + d) * SLEN + st * 64 + sc;
    *(bf16x8*)dst       = *(bf16x8*)&tmp[0];
    *(bf16x8*)(dst + 8) = *(bf16x8*)&tmp[8];
  }
}

// ---------------- Flash attention (Round-4, unchanged) ----------------------
__global__ __launch_bounds__(256) void attn_kernel(
    const bf16_t* Q, const bf16_t* __restrict__ Kg,
    const bf16_t* __restrict__ VT, bf16_t* O)
{
  const int pid = blockIdx.x;        // 0..7
  const int h   = blockIdx.y;
  const int b   = blockIdx.z;
  const int kvh = h >> 2;

  const int tid  = threadIdx.x;
  const int lane = tid & 63;
  const int w    = tid >> 6;
  const int fr   = lane & 15;
  const int quad = lane >> 4;

  const int PS  = 72;
  const int VTS = 136;
  __shared__ __align__(16) bf16_t KL[8192];
  __shared__ __align__(16) bf16_t PP[128 * 72];
  __shared__ __align__(16) bf16_t Vt[64 * 136];

  const size_t qbase = (size_t)b * SLEN;
  const bf16_t* VTh = VT + (size_t)(b * NKVH + kvh) * HDIM * SLEN;

  bf16x8 ones8;
  {
    const bf16_t o1 = (bf16_t)(fr == 0 ? 1.0f : 0.0f);
    for (int j = 0; j < 8; ++j) ones8[j] = o1;
  }

  for (int half = 0; half < 2; ++half) {
    const int qt = half ? (15 - pid) : pid;
    const int q0 = qt * 128;

    bf16x8 qf[2][2];
    for (int qi = 0; qi < 2; ++qi)
      for (int ks = 0; ks < 2; ++ks) {
        const size_t qrow = qbase + q0 + w * 32 + qi * 16 + fr;
        qf[qi][ks] = *(const bf16x8*)&Q[qrow * HID + h * HDIM + ks * 32 + quad * 8];
      }

    const f32x4 z4 = {0.f, 0.f, 0.f, 0.f};
    f32x4 o_acc[2][4];
    f32x4 o_l[2];
    for (int qi = 0; qi < 2; ++qi) {
      o_l[qi] = z4;
      for (int di = 0; di < 4; ++di) o_acc[qi][di] = z4;
    }

    for (int kt = 0; kt <= qt; ++kt) {
      const size_t krow0 = qbase + kt * 128;

      for (int t = 0; t < 4; ++t) {
        const int c  = w * 4 + t;
        const int hf = c >> 3;
        const int r  = (c & 7) * 16 + (lane >> 2);
        const int dk = hf * 32 + (lane & 3) * 8;
        gl2lds16(&Kg[(krow0 + r) * KVW + kvh * HDIM + dk], &KL[c * 512 + lane * 8]);
      }
      {
        const int d  = tid >> 2;
        const int kc = (tid & 3) * 32;
        const bf16_t* src = VTh + (size_t)d * SLEN + kt * 128 + kc;
        bf16x8 v0 = *(const bf16x8*)(src);
        bf16x8 v1 = *(const bf16x8*)(src + 8);
        bf16x8 v2 = *(const bf16x8*)(src + 16);
        bf16x8 v3 = *(const bf16x8*)(src + 24);
        bf16_t* dst = &Vt[d * VTS + kc];
        *(bf16x8*)(dst)      = v0;
        *(bf16x8*)(dst + 8)  = v1;
        *(bf16x8*)(dst + 16) = v2;
        *(bf16x8*)(dst + 24) = v3;
      }
      __syncthreads();

      f32x4 s[2][8];
      for (int qi = 0; qi < 2; ++qi)
        for (int ki = 0; ki < 8; ++ki) s[qi][ki] = z4;
      for (int ks = 0; ks < 2; ++ks)
        for (int ki = 0; ki < 8; ++ki) {
          bf16x8 kf = *(const bf16x8*)&KL[ks * 4096 + (ki * 16 + fr) * 32 + quad * 8];
          s[0][ki] = mfma16(qf[0][ks], kf, s[0][ki]);
          s[1][ki] = mfma16(qf[1][ks], kf, s[1][ki]);
        }

      const float C2 = 0.18033688f;   // log2(e)/8
      const bool diag = (kt == qt);
      for (int hk = 0; hk < 2; ++hk) {
        for (int qi = 0; qi < 2; ++qi)
          for (int k2 = 0; k2 < 4; ++k2) {
            const int ki = hk * 4 + k2;
            for (int r = 0; r < 4; ++r) {
              float pe = fast_exp2(s[qi][ki][r] * C2);
              if (diag && (ki * 16 + fr > w * 32 + qi * 16 + quad * 4 + r))
                pe = 0.f;
              PP[(w * 32 + qi * 16 + quad * 4 + r) * PS + k2 * 16 + fr] =
                  (bf16_t)pe;
            }
          }
        for (int k2 = 0; k2 < 2; ++k2) {
          bf16x8 pf0 = *(const bf16x8*)&PP[(w * 32 + fr) * PS + k2 * 32 + quad * 8];
          bf16x8 pf1 = *(const bf16x8*)&PP[(w * 32 + 16 + fr) * PS + k2 * 32 + quad * 8];
          o_l[0] = mfma16(pf0, ones8, o_l[0]);
          o_l[1] = mfma16(pf1, ones8, o_l[1]);
          const int kb = hk * 64 + k2 * 32;
          for (int di = 0; di < 4; ++di) {
            bf16x8 vf = *(const bf16x8*)&Vt[(di * 16 + fr) * VTS + kb + quad * 8];
            o_acc[0][di] = mfma16(pf0, vf, o_acc[0][di]);
            o_acc[1][di] = mfma16(pf1, vf, o_acc[1][di]);
          }
        }
      }
      __syncthreads();
    }

    for (int qi = 0; qi < 2; ++qi)
      for (int r = 0; r < 4; ++r) {
        const float l  = __shfl(o_l[qi][r], lane & 48);
        const float rl = 1.f / l;
        const size_t qg_ = qbase + q0 + w * 32 + qi * 16 + quad * 4 + r;
        for (int di = 0; di < 4; ++di)
          O[qg_ * HID + h * HDIM + di * 16 + fr] = (bf16_t)(o_acc[qi][di][r] * rl);
      }
  }
}

extern "C" void kernel_launch(void* const* d_in, const int* in_sizes, int n_in,
                              void* d_out, int out_size, void* d_ws, size_t ws_size,
                              hipStream_t stream) {
  const float* x  = (const float*)d_in[0];
  // d_in[1] = causal mask (int32) -- recomputed inline, not read
  const float* Wq = (const float*)d_in[2];
  const float* bq = (const float*)d_in[3];
  const float* Wk = (const float*)d_in[4];
  const float* bk = (const float*)d_in[5];
  const float* Wv = (const float*)d_in[6];
  const float* bv = (const float*)d_in[7];
  const float* Wo = (const float*)d_in[8];
  const float* bo = (const float*)d_in[9];
  float* out = (float*)d_out;

  const size_t M = (size_t)NB * SLEN;          // 4096
  dim3 blk(256, 1, 1);

  // Path A workspace: xb, Wqb, Wkb, Wvb, Wob, Qb, Kb, VbT (all bf16)
  const size_t needA = (M * HID            // xb
                        + (size_t)HID * HID    // Wqb
                        + (size_t)KVW * HID    // Wkb
                        + (size_t)KVW * HID    // Wvb
                        + (size_t)HID * HID    // Wob
                        + M * HID              // Qb
                        + M * KVW              // Kb
                        + M * KVW) * 2;        // VbT
  if (ws_size >= needA) {
    bf16_t* xb  = (bf16_t*)d_ws;
    bf16_t* Wqb = xb  + M * HID;
    bf16_t* Wkb = Wqb + (size_t)HID * HID;
    bf16_t* Wvb = Wkb + (size_t)KVW * HID;
    bf16_t* Wob = Wvb + (size_t)KVW * HID;
    bf16_t* Qb  = Wob + (size_t)HID * HID;
    bf16_t* Kb  = Qb  + M * HID;
    bf16_t* VbT = Kb  + M * KVW;

    cvt_kernel<<<dim3(1024, 5, 1), blk, 0, stream>>>(
        x, Wq, Wk, Wv, Wo, xb, Wqb, Wkb, Wvb, Wob);
    qkv_dma_kernel<<<dim3(24, 32, 1), blk, 0, stream>>>(
        xb, Wqb, bq, Wkb, bk, Wvb, bv, Qb, Kb, VbT);
    attn_kernel<<<dim3(8, 32, 2), blk, 0, stream>>>(Qb, Kb, VbT, Qb);
    oproj_dma_kernel<<<dim3(16, 32, 1), blk, 0, stream>>>(Qb, Wob, bo, out);
  } else {
    // Path B: Round-4 structure (fp32-source GEMMs + vtrans)
    bf16_t* Qb  = (bf16_t*)d_ws;
    bf16_t* Kb  = Qb + M * HID;
    bf16_t* Vb  = Kb + M * KVW;
    bf16_t* VbT = Vb + M * KVW;

    qkv_kernel<<<dim3(24, 32, 1), blk, 0, stream>>>(x, Wq, bq, Wk, bk, Wv, bv, Qb, Kb, Vb);
    vtrans_kernel<<<dim3(32, 8, 2), blk, 0, stream>>>(Vb, VbT);
    attn_kernel<<<dim3(8, 32, 2), blk, 0, stream>>>(Qb, Kb, VbT, Qb);
    oproj_kernel<<<dim3(16, 32, 1), blk, 0, stream>>>(Qb, Wo, bo, out);
  }
}

// Round 6
// 325.910 us; speedup vs baseline: 2.3256x; 1.0367x over previous
//
#include <hip/hip_runtime.h>
#include <hip/hip_bf16.h>
#include <stdint.h>

#define HID   2048
#define SLEN  2048
#define NB    2
#define NHEADS 32
#define NKVH   8
#define HDIM   64
#define KVW    512   // NKVH*HDIM

typedef __bf16 bf16_t;
typedef __bf16 bf16x4 __attribute__((ext_vector_type(4)));
typedef __bf16 bf16x8 __attribute__((ext_vector_type(8)));
typedef float  f32x4  __attribute__((ext_vector_type(4)));

__device__ __forceinline__ f32x4 mfma16(bf16x8 a, bf16x8 b, f32x4 c) {
  return __builtin_amdgcn_mfma_f32_16x16x32_bf16(a, b, c, 0, 0, 0);
}

__device__ __forceinline__ void gl2lds16(const bf16_t* g, bf16_t* l) {
  __builtin_amdgcn_global_load_lds(
      (const __attribute__((address_space(1))) void*)g,
      (__attribute__((address_space(3))) void*)l,
      16, 0, 0);
}

__device__ __forceinline__ float fast_exp2(float x) {
#if __has_builtin(__builtin_amdgcn_exp2f)
  return __builtin_amdgcn_exp2f(x);
#else
  return __expf(x * 0.69314718f);
#endif
}

__device__ __forceinline__ bf16x8 ld8(const bf16_t* p) {
  return *(const bf16x8*)p;
}
__device__ __forceinline__ bf16x8 ld8(const float* p) {
  f32x4 a = *(const f32x4*)p;
  f32x4 b = *(const f32x4*)(p + 4);
  bf16x8 r;
  r[0] = (bf16_t)a[0]; r[1] = (bf16_t)a[1]; r[2] = (bf16_t)a[2]; r[3] = (bf16_t)a[3];
  r[4] = (bf16_t)b[0]; r[5] = (bf16_t)b[1]; r[6] = (bf16_t)b[2]; r[7] = (bf16_t)b[3];
  return r;
}

__device__ __forceinline__ void st_c(bf16_t* p, float v) { *p = (bf16_t)v; }
__device__ __forceinline__ void st_c(float*  p, float v) { *p = v; }

// ---------------- fp32 -> bf16 convert pass (Path A prologue) ---------------
__global__ __launch_bounds__(256) void cvt_kernel(
    const float* __restrict__ x,  const float* __restrict__ wq,
    const float* __restrict__ wk, const float* __restrict__ wv,
    const float* __restrict__ wo,
    bf16_t* xb, bf16_t* wqb, bf16_t* wkb, bf16_t* wvb, bf16_t* wob)
{
  const float* s; bf16_t* d; size_t n;
  switch (blockIdx.y) {
    case 0:  s = x;  d = xb;  n = (size_t)NB * SLEN * HID; break;
    case 1:  s = wq; d = wqb; n = (size_t)HID * HID; break;
    case 2:  s = wk; d = wkb; n = (size_t)KVW * HID; break;
    case 3:  s = wv; d = wvb; n = (size_t)KVW * HID; break;
    default: s = wo; d = wob; n = (size_t)HID * HID; break;
  }
  const size_t stride = (size_t)gridDim.x * 256 * 8;
  for (size_t i = ((size_t)blockIdx.x * 256 + threadIdx.x) * 8; i < n; i += stride)
    *(bf16x8*)(d + i) = ld8(s + i);
}

// ---------------- BK=64 pure-bf16 GEMM tile (DMA staging) -------------------
// C = A * W^T + bias over a 128x128 tile, K-loop step 64.
// LDS layout per matrix: [kh][128 rows][32 k] (two 8-KB halves) -- 64-B rows,
// DMA-contiguous 1-KB chunks, same conflict profile as the verified m97 shape.
// TRANSV: store C transposed (Cp[col*ldc + row], bf16x4-packed) for VbT.
template <typename CT, bool TRANSV>
__device__ __forceinline__ void gemm128_dma(
    const bf16_t* __restrict__ Ap, int lda,
    const bf16_t* __restrict__ Wp, int ldw,
    const float* __restrict__ biasp,
    CT* __restrict__ Cp, int ldc, int K)
{
  __shared__ __align__(16) bf16_t Al[2 * 4096];
  __shared__ __align__(16) bf16_t Bl[2 * 4096];

  const int tid  = threadIdx.x;
  const int lane = tid & 63;
  const int w    = tid >> 6;
  const int fr   = lane & 15;
  const int quad = lane >> 4;
  const int wm   = (w >> 1) * 64;
  const int wn   = (w & 1) * 64;

  const f32x4 z4 = {0.f, 0.f, 0.f, 0.f};
  f32x4 acc[4][4];
  for (int i = 0; i < 4; ++i)
    for (int j = 0; j < 4; ++j) acc[i][j] = z4;

  // chunk c (0..15): kh=c>>3, rows (c&7)*16 + (lane>>2), k = kh*32+(lane&3)*8
  const int c0   = w * 4;
  const int srow = lane >> 2;
  const int skc  = (lane & 3) * 8;

  for (int k0 = 0; k0 < K; k0 += 64) {
    for (int t = 0; t < 4; ++t) {
      const int c  = c0 + t;
      const int r  = (c & 7) * 16 + srow;
      const int kk = k0 + (c >> 3) * 32 + skc;
      gl2lds16(Ap + (size_t)r * lda + kk, &Al[c * 512 + lane * 8]);
      gl2lds16(Wp + (size_t)r * ldw + kk, &Bl[c * 512 + lane * 8]);
    }
    __syncthreads();   // drains vmcnt (compiler emits waitcnt before barrier)
    for (int ks = 0; ks < 2; ++ks) {
      bf16x8 af[4], bfr[4];
      for (int mi = 0; mi < 4; ++mi)
        af[mi] = *(const bf16x8*)&Al[ks * 4096 + (wm + mi * 16 + fr) * 32 + quad * 8];
      for (int ni = 0; ni < 4; ++ni)
        bfr[ni] = *(const bf16x8*)&Bl[ks * 4096 + (wn + ni * 16 + fr) * 32 + quad * 8];
      for (int mi = 0; mi < 4; ++mi)
        for (int ni = 0; ni < 4; ++ni)
          acc[mi][ni] = mfma16(af[mi], bfr[ni], acc[mi][ni]);
    }
    __syncthreads();
  }

  // Epilogue: C/D layout col=lane&15, row=quad*4+reg (m89/m91 verified).
  for (int ni = 0; ni < 4; ++ni) {
    const int col = wn + ni * 16 + fr;
    const float bz = biasp[col];
    for (int mi = 0; mi < 4; ++mi) {
      const int r0 = wm + mi * 16 + quad * 4;
      if constexpr (TRANSV) {
        bf16x4 pk;
        for (int r = 0; r < 4; ++r) pk[r] = (bf16_t)(acc[mi][ni][r] + bz);
        *(bf16x4*)&Cp[(size_t)col * ldc + r0] = pk;
      } else {
        for (int r = 0; r < 4; ++r)
          st_c(Cp + (size_t)(r0 + r) * ldc + col, acc[mi][ni][r] + bz);
      }
    }
  }
}

// Path A QKV: pure-bf16 inputs; V written directly transposed into VbT.
__global__ __launch_bounds__(256) void qkv_dma_kernel(
    const bf16_t* __restrict__ xb,
    const bf16_t* __restrict__ Wqb, const float* __restrict__ bq,
    const bf16_t* __restrict__ Wkb, const float* __restrict__ bk,
    const bf16_t* __restrict__ Wvb, const float* __restrict__ bv,
    bf16_t* Qb, bf16_t* Kb, bf16_t* VbT)
{
  const int nb = blockIdx.x;   // 16 Q, 4 K, 4 V
  const int mb = blockIdx.y;   // 32
  const bf16_t* A = xb + (size_t)mb * 128 * HID;
  if (nb < 16) {
    gemm128_dma<bf16_t, false>(A, HID, Wqb + (size_t)nb * 128 * HID, HID,
                               bq + nb * 128,
                               Qb + (size_t)mb * 128 * HID + nb * 128, HID, HID);
  } else if (nb < 20) {
    const int j = nb - 16;
    gemm128_dma<bf16_t, false>(A, HID, Wkb + (size_t)j * 128 * HID, HID,
                               bk + j * 128,
                               Kb + (size_t)mb * 128 * KVW + j * 128, KVW, HID);
  } else {
    const int j = nb - 20;        // V block: cols j*128.. = kvh {2j, 2j+1}
    const int b = mb >> 4;        // batch; s_in_b = (mb&15)*128 + local row
    bf16_t* Cv = VbT + ((size_t)(b * NKVH + j * 2) * HDIM) * SLEN + (mb & 15) * 128;
    gemm128_dma<bf16_t, true>(A, HID, Wvb + (size_t)j * 128 * HID, HID,
                              bv + j * 128, Cv, SLEN, HID);
  }
}

__global__ __launch_bounds__(256) void oproj_dma_kernel(
    const bf16_t* __restrict__ A, const bf16_t* __restrict__ Wob,
    const float* __restrict__ bo, float* out)
{
  const int nb = blockIdx.x, mb = blockIdx.y;
  gemm128_dma<float, false>(A + (size_t)mb * 128 * HID, HID,
                            Wob + (size_t)nb * 128 * HID, HID,
                            bo + nb * 128,
                            out + (size_t)mb * 128 * HID + nb * 128, HID, HID);
}

// ---------------- Path B (fallback): fp32-source GEMM -----------------------
template <typename AT, typename CT>
__device__ __forceinline__ void gemm128_tile(
    const AT* __restrict__ Ap, int lda,
    const float* __restrict__ Wp, int ldw,
    const float* __restrict__ biasp,
    CT* __restrict__ Cp, int ldc,
    int K)
{
  __shared__ __align__(16) bf16_t Al[128 * 32];
  __shared__ __align__(16) bf16_t Bl[128 * 32];

  const int tid  = threadIdx.x;
  const int lane = tid & 63;
  const int w    = tid >> 6;
  const int fr   = lane & 15;
  const int quad = lane >> 4;
  const int wm   = (w >> 1) * 64;
  const int wn   = (w & 1) * 64;

  const f32x4 z4 = {0.f, 0.f, 0.f, 0.f};
  f32x4 acc[4][4];
  for (int i = 0; i < 4; ++i)
    for (int j = 0; j < 4; ++j) acc[i][j] = z4;

  const int c0    = w * 2;
  const int srow0 = lane >> 2;
  const int skc   = (lane & 3) * 8;

  for (int k0 = 0; k0 < K; k0 += 32) {
    bf16x8 av[2], bv[2];
    for (int t = 0; t < 2; ++t) {
      const int r = (c0 + t) * 16 + srow0;
      av[t] = ld8(Ap + (size_t)r * lda + k0 + skc);
      bv[t] = ld8(Wp + (size_t)r * ldw + k0 + skc);
    }
    for (int t = 0; t < 2; ++t) {
      const int c = c0 + t;
      *(bf16x8*)&Al[c * 512 + lane * 8] = av[t];
      *(bf16x8*)&Bl[c * 512 + lane * 8] = bv[t];
    }
    __syncthreads();
    bf16x8 af[4], bfr[4];
    for (int mi = 0; mi < 4; ++mi)
      af[mi] = *(const bf16x8*)&Al[(wm + mi * 16 + fr) * 32 + quad * 8];
    for (int ni = 0; ni < 4; ++ni)
      bfr[ni] = *(const bf16x8*)&Bl[(wn + ni * 16 + fr) * 32 + quad * 8];
    for (int mi = 0; mi < 4; ++mi)
      for (int ni = 0; ni < 4; ++ni)
        acc[mi][ni] = mfma16(af[mi], bfr[ni], acc[mi][ni]);
    __syncthreads();
  }

  for (int ni = 0; ni < 4; ++ni) {
    const int col = wn + ni * 16 + fr;
    const float bz = biasp[col];
    for (int mi = 0; mi < 4; ++mi) {
      const int r0 = wm + mi * 16 + quad * 4;
      for (int r = 0; r < 4; ++r)
        st_c(Cp + (size_t)(r0 + r) * ldc + col, acc[mi][ni][r] + bz);
    }
  }
}

__global__ __launch_bounds__(256) void qkv_kernel(
    const float* __restrict__ x,
    const float* __restrict__ Wq, const float* __restrict__ bq,
    const float* __restrict__ Wk, const float* __restrict__ bk,
    const float* __restrict__ Wv, const float* __restrict__ bv,
    bf16_t* Qb, bf16_t* Kb, bf16_t* Vb)
{
  const int nb = blockIdx.x;
  const int mb = blockIdx.y;
  const float* W; const float* bias; bf16_t* C; int ldc;
  if (nb < 16)      { W = Wq + (size_t)nb * 128 * HID;  bias = bq + nb * 128;
                      C = Qb + nb * 128; ldc = HID; }
  else if (nb < 20) { const int j = nb - 16;
                      W = Wk + (size_t)j * 128 * HID;   bias = bk + j * 128;
                      C = Kb + j * 128; ldc = KVW; }
  else              { const int j = nb - 20;
                      W = Wv + (size_t)j * 128 * HID;   bias = bv + j * 128;
                      C = Vb + j * 128; ldc = KVW; }
  gemm128_tile<float, bf16_t>(x + (size_t)mb * 128 * HID, HID, W, HID, bias,
                              C + (size_t)mb * 128 * ldc, ldc, HID);
}

__global__ __launch_bounds__(256) void oproj_kernel(
    const bf16_t* __restrict__ A, const float* __restrict__ Wo,
    const float* __restrict__ bo, float* out)
{
  const int nb = blockIdx.x, mb = blockIdx.y;
  gemm128_tile<bf16_t, float>(A + (size_t)mb * 128 * HID, HID,
                              Wo + (size_t)nb * 128 * HID, HID,
                              bo + nb * 128,
                              out + (size_t)mb * 128 * HID + nb * 128, HID, HID);
}

__global__ __launch_bounds__(256) void vtrans_kernel(
    const bf16_t* __restrict__ Vb, bf16_t* __restrict__ VbT)
{
  __shared__ bf16_t T[64][72];
  const int st = blockIdx.x, kvh = blockIdx.y, b = blockIdx.z;
  const int tid = threadIdx.x;
  {
    const int row = tid >> 2;
    const int c16 = (tid & 3) * 16;
    const bf16_t* src =
        Vb + ((size_t)b * SLEN + st * 64 + row) * KVW + kvh * HDIM + c16;
    *(bf16x8*)&T[row][c16]     = *(const bf16x8*)(src);
    *(bf16x8*)&T[row][c16 + 8] = *(const bf16x8*)(src + 8);
  }
  __syncthreads();
  {
    const int d  = tid >> 2;
    const int sc = (tid & 3) * 16;
    bf16_t tmp[16];
    for (int j = 0; j < 16; ++j) tmp[j] = T[sc + j][d];
    bf16_t* dst = VbT + ((size_t)(b * NKVH + kvh) * HDIM + d) * SLEN + st * 64 + sc;
    *(bf16x8*)dst       = *(bf16x8*)&tmp[0];
    *(bf16x8*)(dst + 8) = *(bf16x8*)&tmp[8];
  }
}

// ---------------- Flash attention (unchanged) -------------------------------
__global__ __launch_bounds__(256) void attn_kernel(
    const bf16_t* Q, const bf16_t* __restrict__ Kg,
    const bf16_t* __restrict__ VT, bf16_t* O)
{
  const int pid = blockIdx.x;        // 0..7
  const int h   = blockIdx.y;
  const int b   = blockIdx.z;
  const int kvh = h >> 2;

  const int tid  = threadIdx.x;
  const int lane = tid & 63;
  const int w    = tid >> 6;
  const int fr   = lane & 15;
  const int quad = lane >> 4;

  const int PS  = 72;
  const int VTS = 136;
  __shared__ __align__(16) bf16_t KL[8192];
  __shared__ __align__(16) bf16_t PP[128 * 72];
  __shared__ __align__(16) bf16_t Vt[64 * 136];

  const size_t qbase = (size_t)b * SLEN;
  const bf16_t* VTh = VT + (size_t)(b * NKVH + kvh) * HDIM * SLEN;

  bf16x8 ones8;
  {
    const bf16_t o1 = (bf16_t)(fr == 0 ? 1.0f : 0.0f);
    for (int j = 0; j < 8; ++j) ones8[j] = o1;
  }

  for (int half = 0; half < 2; ++half) {
    const int qt = half ? (15 - pid) : pid;
    const int q0 = qt * 128;

    bf16x8 qf[2][2];
    for (int qi = 0; qi < 2; ++qi)
      for (int ks = 0; ks < 2; ++ks) {
        const size_t qrow = qbase + q0 + w * 32 + qi * 16 + fr;
        qf[qi][ks] = *(const bf16x8*)&Q[qrow * HID + h * HDIM + ks * 32 + quad * 8];
      }

    const f32x4 z4 = {0.f, 0.f, 0.f, 0.f};
    f32x4 o_acc[2][4];
    f32x4 o_l[2];
    for (int qi = 0; qi < 2; ++qi) {
      o_l[qi] = z4;
      for (int di = 0; di < 4; ++di) o_acc[qi][di] = z4;
    }

    for (int kt = 0; kt <= qt; ++kt) {
      const size_t krow0 = qbase + kt * 128;

      for (int t = 0; t < 4; ++t) {
        const int c  = w * 4 + t;
        const int hf = c >> 3;
        const int r  = (c & 7) * 16 + (lane >> 2);
        const int dk = hf * 32 + (lane & 3) * 8;
        gl2lds16(&Kg[(krow0 + r) * KVW + kvh * HDIM + dk], &KL[c * 512 + lane * 8]);
      }
      {
        const int d  = tid >> 2;
        const int kc = (tid & 3) * 32;
        const bf16_t* src = VTh + (size_t)d * SLEN + kt * 128 + kc;
        bf16x8 v0 = *(const bf16x8*)(src);
        bf16x8 v1 = *(const bf16x8*)(src + 8);
        bf16x8 v2 = *(const bf16x8*)(src + 16);
        bf16x8 v3 = *(const bf16x8*)(src + 24);
        bf16_t* dst = &Vt[d * VTS + kc];
        *(bf16x8*)(dst)      = v0;
        *(bf16x8*)(dst + 8)  = v1;
        *(bf16x8*)(dst + 16) = v2;
        *(bf16x8*)(dst + 24) = v3;
      }
      __syncthreads();

      f32x4 s[2][8];
      for (int qi = 0; qi < 2; ++qi)
        for (int ki = 0; ki < 8; ++ki) s[qi][ki] = z4;
      for (int ks = 0; ks < 2; ++ks)
        for (int ki = 0; ki < 8; ++ki) {
          bf16x8 kf = *(const bf16x8*)&KL[ks * 4096 + (ki * 16 + fr) * 32 + quad * 8];
          s[0][ki] = mfma16(qf[0][ks], kf, s[0][ki]);
          s[1][ki] = mfma16(qf[1][ks], kf, s[1][ki]);
        }

      const float C2 = 0.18033688f;   // log2(e)/8
      const bool diag = (kt == qt);
      for (int hk = 0; hk < 2; ++hk) {
        for (int qi = 0; qi < 2; ++qi)
          for (int k2 = 0; k2 < 4; ++k2) {
            const int ki = hk * 4 + k2;
            for (int r = 0; r < 4; ++r) {
              float pe = fast_exp2(s[qi][ki][r] * C2);
              if (diag && (ki * 16 + fr > w * 32 + qi * 16 + quad * 4 + r))
                pe = 0.f;
              PP[(w * 32 + qi * 16 + quad * 4 + r) * PS + k2 * 16 + fr] =
                  (bf16_t)pe;
            }
          }
        for (int k2 = 0; k2 < 2; ++k2) {
          bf16x8 pf0 = *(const bf16x8*)&PP[(w * 32 + fr) * PS + k2 * 32 + quad * 8];
          bf16x8 pf1 = *(const bf16x8*)&PP[(w * 32 + 16 + fr) * PS + k2 * 32 + quad * 8];
          o_l[0] = mfma16(pf0, ones8, o_l[0]);
          o_l[1] = mfma16(pf1, ones8, o_l[1]);
          const int kb = hk * 64 + k2 * 32;
          for (int di = 0; di < 4; ++di) {
            bf16x8 vf = *(const bf16x8*)&Vt[(di * 16 + fr) * VTS + kb + quad * 8];
            o_acc[0][di] = mfma16(pf0, vf, o_acc[0][di]);
            o_acc[1][di] = mfma16(pf1, vf, o_acc[1][di]);
          }
        }
      }
      __syncthreads();
    }

    for (int qi = 0; qi < 2; ++qi)
      for (int r = 0; r < 4; ++r) {
        const float l  = __shfl(o_l[qi][r], lane & 48);
        const float rl = 1.f / l;
        const size_t qg_ = qbase + q0 + w * 32 + qi * 16 + quad * 4 + r;
        for (int di = 0; di < 4; ++di)
          O[qg_ * HID + h * HDIM + di * 16 + fr] = (bf16_t)(o_acc[qi][di][r] * rl);
      }
  }
}

extern "C" void kernel_launch(void* const* d_in, const int* in_sizes, int n_in,
                              void* d_out, int out_size, void* d_ws, size_t ws_size,
                              hipStream_t stream) {
  const float* x  = (const float*)d_in[0];
  // d_in[1] = causal mask (int32) -- recomputed inline, not read
  const float* Wq = (const float*)d_in[2];
  const float* bq = (const float*)d_in[3];
  const float* Wk = (const float*)d_in[4];
  const float* bk = (const float*)d_in[5];
  const float* Wv = (const float*)d_in[6];
  const float* bv = (const float*)d_in[7];
  const float* Wo = (const float*)d_in[8];
  const float* bo = (const float*)d_in[9];
  float* out = (float*)d_out;

  const size_t M = (size_t)NB * SLEN;          // 4096
  dim3 blk(256, 1, 1);

  const size_t needA = (M * HID
                        + (size_t)HID * HID
                        + (size_t)KVW * HID
                        + (size_t)KVW * HID
                        + (size_t)HID * HID
                        + M * HID
                        + M * KVW
                        + M * KVW) * 2;
  if (ws_size >= needA) {
    bf16_t* xb  = (bf16_t*)d_ws;
    bf16_t* Wqb = xb  + M * HID;
    bf16_t* Wkb = Wqb + (size_t)HID * HID;
    bf16_t* Wvb = Wkb + (size_t)KVW * HID;
    bf16_t* Wob = Wvb + (size_t)KVW * HID;
    bf16_t* Qb  = Wob + (size_t)HID * HID;
    bf16_t* Kb  = Qb  + M * HID;
    bf16_t* VbT = Kb  + M * KVW;

    cvt_kernel<<<dim3(1024, 5, 1), blk, 0, stream>>>(
        x, Wq, Wk, Wv, Wo, xb, Wqb, Wkb, Wvb, Wob);
    qkv_dma_kernel<<<dim3(24, 32, 1), blk, 0, stream>>>(
        xb, Wqb, bq, Wkb, bk, Wvb, bv, Qb, Kb, VbT);
    attn_kernel<<<dim3(8, 32, 2), blk, 0, stream>>>(Qb, Kb, VbT, Qb);
    oproj_dma_kernel<<<dim3(16, 32, 1), blk, 0, stream>>>(Qb, Wob, bo, out);
  } else {
    bf16_t* Qb  = (bf16_t*)d_ws;
    bf16_t* Kb  = Qb + M * HID;
    bf16_t* Vb  = Kb + M * KVW;
    bf16_t* VbT = Vb + M * KVW;

    qkv_kernel<<<dim3(24, 32, 1), blk, 0, stream>>>(x, Wq, bq, Wk, bk, Wv, bv, Qb, Kb, Vb);
    vtrans_kernel<<<dim3(32, 8, 2), blk, 0, stream>>>(Vb, VbT);
    attn_kernel<<<dim3(8, 32, 2), blk, 0, stream>>>(Qb, Kb, VbT, Qb);
    oproj_kernel<<<dim3(16, 32, 1), blk, 0, stream>>>(Qb, Wo, bo, out);
  }
}

// Round 7
// 325.264 us; speedup vs baseline: 2.3302x; 1.0020x over previous
//
#include <hip/hip_runtime.h>
#include <hip/hip_bf16.h>
#include <stdint.h>

#define HID   2048
#define SLEN  2048
#define NB    2
#define NHEADS 32
#define NKVH   8
#define HDIM   64
#define KVW    512   // NKVH*HDIM

typedef __bf16 bf16_t;
typedef __bf16 bf16x4 __attribute__((ext_vector_type(4)));
typedef __bf16 bf16x8 __attribute__((ext_vector_type(8)));
typedef float  f32x4  __attribute__((ext_vector_type(4)));

__device__ __forceinline__ f32x4 mfma16(bf16x8 a, bf16x8 b, f32x4 c) {
  return __builtin_amdgcn_mfma_f32_16x16x32_bf16(a, b, c, 0, 0, 0);
}

__device__ __forceinline__ void gl2lds16(const bf16_t* g, bf16_t* l) {
  __builtin_amdgcn_global_load_lds(
      (const __attribute__((address_space(1))) void*)g,
      (__attribute__((address_space(3))) void*)l,
      16, 0, 0);
}

__device__ __forceinline__ float fast_exp2(float x) {
#if __has_builtin(__builtin_amdgcn_exp2f)
  return __builtin_amdgcn_exp2f(x);
#else
  return __expf(x * 0.69314718f);
#endif
}

__device__ __forceinline__ bf16x8 ld8(const bf16_t* p) {
  return *(const bf16x8*)p;
}
__device__ __forceinline__ bf16x8 ld8(const float* p) {
  f32x4 a = *(const f32x4*)p;
  f32x4 b = *(const f32x4*)(p + 4);
  bf16x8 r;
  r[0] = (bf16_t)a[0]; r[1] = (bf16_t)a[1]; r[2] = (bf16_t)a[2]; r[3] = (bf16_t)a[3];
  r[4] = (bf16_t)b[0]; r[5] = (bf16_t)b[1]; r[6] = (bf16_t)b[2]; r[7] = (bf16_t)b[3];
  return r;
}

__device__ __forceinline__ void st_c(bf16_t* p, float v) { *p = (bf16_t)v; }
__device__ __forceinline__ void st_c(float*  p, float v) { *p = v; }

// ---------------- fp32 -> bf16 convert pass (Path A prologue) ---------------
__global__ __launch_bounds__(256) void cvt_kernel(
    const float* __restrict__ x,  const float* __restrict__ wq,
    const float* __restrict__ wk, const float* __restrict__ wv,
    const float* __restrict__ wo,
    bf16_t* xb, bf16_t* wqb, bf16_t* wkb, bf16_t* wvb, bf16_t* wob)
{
  const float* s; bf16_t* d; size_t n;
  switch (blockIdx.y) {
    case 0:  s = x;  d = xb;  n = (size_t)NB * SLEN * HID; break;
    case 1:  s = wq; d = wqb; n = (size_t)HID * HID; break;
    case 2:  s = wk; d = wkb; n = (size_t)KVW * HID; break;
    case 3:  s = wv; d = wvb; n = (size_t)KVW * HID; break;
    default: s = wo; d = wob; n = (size_t)HID * HID; break;
  }
  const size_t stride = (size_t)gridDim.x * 256 * 8;
  for (size_t i = ((size_t)blockIdx.x * 256 + threadIdx.x) * 8; i < n; i += stride)
    *(bf16x8*)(d + i) = ld8(s + i);
}

// ---------------- BK=64 pure-bf16 GEMM tile (DMA staging) -------------------
// LDS buffers are passed in (single kernel-scope allocation, 32 KB total),
// so multiple template instantiations in one kernel share one allocation.
// Layout per matrix: [kh][128 rows][32 k] (two 8-KB halves).
// TRANSV: store C transposed (Cp[col*ldc + row], bf16x4-packed) for VbT.
template <typename CT, bool TRANSV>
__device__ __forceinline__ void gemm128_dma(
    const bf16_t* __restrict__ Ap, int lda,
    const bf16_t* __restrict__ Wp, int ldw,
    const float* __restrict__ biasp,
    CT* __restrict__ Cp, int ldc, int K,
    bf16_t* __restrict__ Al, bf16_t* __restrict__ Bl)
{
  const int tid  = threadIdx.x;
  const int lane = tid & 63;
  const int w    = tid >> 6;
  const int fr   = lane & 15;
  const int quad = lane >> 4;
  const int wm   = (w >> 1) * 64;
  const int wn   = (w & 1) * 64;

  const f32x4 z4 = {0.f, 0.f, 0.f, 0.f};
  f32x4 acc[4][4];
  for (int i = 0; i < 4; ++i)
    for (int j = 0; j < 4; ++j) acc[i][j] = z4;

  // chunk c (0..15): kh=c>>3, rows (c&7)*16 + (lane>>2), k = kh*32+(lane&3)*8
  const int c0   = w * 4;
  const int srow = lane >> 2;
  const int skc  = (lane & 3) * 8;

  for (int k0 = 0; k0 < K; k0 += 64) {
    for (int t = 0; t < 4; ++t) {
      const int c  = c0 + t;
      const int r  = (c & 7) * 16 + srow;
      const int kk = k0 + (c >> 3) * 32 + skc;
      gl2lds16(Ap + (size_t)r * lda + kk, &Al[c * 512 + lane * 8]);
      gl2lds16(Wp + (size_t)r * ldw + kk, &Bl[c * 512 + lane * 8]);
    }
    __syncthreads();   // drains vmcnt (compiler emits waitcnt before barrier)
    for (int ks = 0; ks < 2; ++ks) {
      bf16x8 af[4], bfr[4];
      for (int mi = 0; mi < 4; ++mi)
        af[mi] = *(const bf16x8*)&Al[ks * 4096 + (wm + mi * 16 + fr) * 32 + quad * 8];
      for (int ni = 0; ni < 4; ++ni)
        bfr[ni] = *(const bf16x8*)&Bl[ks * 4096 + (wn + ni * 16 + fr) * 32 + quad * 8];
      for (int mi = 0; mi < 4; ++mi)
        for (int ni = 0; ni < 4; ++ni)
          acc[mi][ni] = mfma16(af[mi], bfr[ni], acc[mi][ni]);
    }
    __syncthreads();
  }

  // Epilogue: C/D layout col=lane&15, row=quad*4+reg (m89/m91 verified).
  for (int ni = 0; ni < 4; ++ni) {
    const int col = wn + ni * 16 + fr;
    const float bz = biasp[col];
    for (int mi = 0; mi < 4; ++mi) {
      const int r0 = wm + mi * 16 + quad * 4;
      if constexpr (TRANSV) {
        bf16x4 pk;
        for (int r = 0; r < 4; ++r) pk[r] = (bf16_t)(acc[mi][ni][r] + bz);
        *(bf16x4*)&Cp[(size_t)col * ldc + r0] = pk;
      } else {
        for (int r = 0; r < 4; ++r)
          st_c(Cp + (size_t)(r0 + r) * ldc + col, acc[mi][ni][r] + bz);
      }
    }
  }
}

// Path A QKV: pure-bf16 inputs; V written directly transposed into VbT.
__global__ __launch_bounds__(256) void qkv_dma_kernel(
    const bf16_t* __restrict__ xb,
    const bf16_t* __restrict__ Wqb, const float* __restrict__ bq,
    const bf16_t* __restrict__ Wkb, const float* __restrict__ bk,
    const bf16_t* __restrict__ Wvb, const float* __restrict__ bv,
    bf16_t* Qb, bf16_t* Kb, bf16_t* VbT)
{
  // One shared staging allocation for all template instantiations (32 KB).
  __shared__ __align__(16) bf16_t Al[2 * 4096];
  __shared__ __align__(16) bf16_t Bl[2 * 4096];

  const int nb = blockIdx.x;   // 16 Q, 4 K, 4 V
  const int mb = blockIdx.y;   // 32
  const bf16_t* A = xb + (size_t)mb * 128 * HID;
  if (nb < 16) {
    gemm128_dma<bf16_t, false>(A, HID, Wqb + (size_t)nb * 128 * HID, HID,
                               bq + nb * 128,
                               Qb + (size_t)mb * 128 * HID + nb * 128, HID, HID,
                               Al, Bl);
  } else if (nb < 20) {
    const int j = nb - 16;
    gemm128_dma<bf16_t, false>(A, HID, Wkb + (size_t)j * 128 * HID, HID,
                               bk + j * 128,
                               Kb + (size_t)mb * 128 * KVW + j * 128, KVW, HID,
                               Al, Bl);
  } else {
    const int j = nb - 20;        // V block: cols j*128.. = kvh {2j, 2j+1}
    const int b = mb >> 4;        // batch; s_in_b = (mb&15)*128 + local row
    bf16_t* Cv = VbT + ((size_t)(b * NKVH + j * 2) * HDIM) * SLEN + (mb & 15) * 128;
    gemm128_dma<bf16_t, true>(A, HID, Wvb + (size_t)j * 128 * HID, HID,
                              bv + j * 128, Cv, SLEN, HID, Al, Bl);
  }
}

__global__ __launch_bounds__(256) void oproj_dma_kernel(
    const bf16_t* __restrict__ A, const bf16_t* __restrict__ Wob,
    const float* __restrict__ bo, float* out)
{
  __shared__ __align__(16) bf16_t Al[2 * 4096];
  __shared__ __align__(16) bf16_t Bl[2 * 4096];
  const int nb = blockIdx.x, mb = blockIdx.y;
  gemm128_dma<float, false>(A + (size_t)mb * 128 * HID, HID,
                            Wob + (size_t)nb * 128 * HID, HID,
                            bo + nb * 128,
                            out + (size_t)mb * 128 * HID + nb * 128, HID, HID,
                            Al, Bl);
}

// ---------------- Path B (fallback): fp32-source GEMM -----------------------
template <typename AT, typename CT>
__device__ __forceinline__ void gemm128_tile(
    const AT* __restrict__ Ap, int lda,
    const float* __restrict__ Wp, int ldw,
    const float* __restrict__ biasp,
    CT* __restrict__ Cp, int ldc,
    int K)
{
  __shared__ __align__(16) bf16_t Al[128 * 32];
  __shared__ __align__(16) bf16_t Bl[128 * 32];

  const int tid  = threadIdx.x;
  const int lane = tid & 63;
  const int w    = tid >> 6;
  const int fr   = lane & 15;
  const int quad = lane >> 4;
  const int wm   = (w >> 1) * 64;
  const int wn   = (w & 1) * 64;

  const f32x4 z4 = {0.f, 0.f, 0.f, 0.f};
  f32x4 acc[4][4];
  for (int i = 0; i < 4; ++i)
    for (int j = 0; j < 4; ++j) acc[i][j] = z4;

  const int c0    = w * 2;
  const int srow0 = lane >> 2;
  const int skc   = (lane & 3) * 8;

  for (int k0 = 0; k0 < K; k0 += 32) {
    bf16x8 av[2], bv[2];
    for (int t = 0; t < 2; ++t) {
      const int r = (c0 + t) * 16 + srow0;
      av[t] = ld8(Ap + (size_t)r * lda + k0 + skc);
      bv[t] = ld8(Wp + (size_t)r * ldw + k0 + skc);
    }
    for (int t = 0; t < 2; ++t) {
      const int c = c0 + t;
      *(bf16x8*)&Al[c * 512 + lane * 8] = av[t];
      *(bf16x8*)&Bl[c * 512 + lane * 8] = bv[t];
    }
    __syncthreads();
    bf16x8 af[4], bfr[4];
    for (int mi = 0; mi < 4; ++mi)
      af[mi] = *(const bf16x8*)&Al[(wm + mi * 16 + fr) * 32 + quad * 8];
    for (int ni = 0; ni < 4; ++ni)
      bfr[ni] = *(const bf16x8*)&Bl[(wn + ni * 16 + fr) * 32 + quad * 8];
    for (int mi = 0; mi < 4; ++mi)
      for (int ni = 0; ni < 4; ++ni)
        acc[mi][ni] = mfma16(af[mi], bfr[ni], acc[mi][ni]);
    __syncthreads();
  }

  for (int ni = 0; ni < 4; ++ni) {
    const int col = wn + ni * 16 + fr;
    const float bz = biasp[col];
    for (int mi = 0; mi < 4; ++mi) {
      const int r0 = wm + mi * 16 + quad * 4;
      for (int r = 0; r < 4; ++r)
        st_c(Cp + (size_t)(r0 + r) * ldc + col, acc[mi][ni][r] + bz);
    }
  }
}

__global__ __launch_bounds__(256) void qkv_kernel(
    const float* __restrict__ x,
    const float* __restrict__ Wq, const float* __restrict__ bq,
    const float* __restrict__ Wk, const float* __restrict__ bk,
    const float* __restrict__ Wv, const float* __restrict__ bv,
    bf16_t* Qb, bf16_t* Kb, bf16_t* Vb)
{
  const int nb = blockIdx.x;
  const int mb = blockIdx.y;
  const float* W; const float* bias; bf16_t* C; int ldc;
  if (nb < 16)      { W = Wq + (size_t)nb * 128 * HID;  bias = bq + nb * 128;
                      C = Qb + nb * 128; ldc = HID; }
  else if (nb < 20) { const int j = nb - 16;
                      W = Wk + (size_t)j * 128 * HID;   bias = bk + j * 128;
                      C = Kb + j * 128; ldc = KVW; }
  else              { const int j = nb - 20;
                      W = Wv + (size_t)j * 128 * HID;   bias = bv + j * 128;
                      C = Vb + j * 128; ldc = KVW; }
  gemm128_tile<float, bf16_t>(x + (size_t)mb * 128 * HID, HID, W, HID, bias,
                              C + (size_t)mb * 128 * ldc, ldc, HID);
}

__global__ __launch_bounds__(256) void oproj_kernel(
    const bf16_t* __restrict__ A, const float* __restrict__ Wo,
    const float* __restrict__ bo, float* out)
{
  const int nb = blockIdx.x, mb = blockIdx.y;
  gemm128_tile<bf16_t, float>(A + (size_t)mb * 128 * HID, HID,
                              Wo + (size_t)nb * 128 * HID, HID,
                              bo + nb * 128,
                              out + (size_t)mb * 128 * HID + nb * 128, HID, HID);
}

__global__ __launch_bounds__(256) void vtrans_kernel(
    const bf16_t* __restrict__ Vb, bf16_t* __restrict__ VbT)
{
  __shared__ bf16_t T[64][72];
  const int st = blockIdx.x, kvh = blockIdx.y, b = blockIdx.z;
  const int tid = threadIdx.x;
  {
    const int row = tid >> 2;
    const int c16 = (tid & 3) * 16;
    const bf16_t* src =
        Vb + ((size_t)b * SLEN + st * 64 + row) * KVW + kvh * HDIM + c16;
    *(bf16x8*)&T[row][c16]     = *(const bf16x8*)(src);
    *(bf16x8*)&T[row][c16 + 8] = *(const bf16x8*)(src + 8);
  }
  __syncthreads();
  {
    const int d  = tid >> 2;
    const int sc = (tid & 3) * 16;
    bf16_t tmp[16];
    for (int j = 0; j < 16; ++j) tmp[j] = T[sc + j][d];
    bf16_t* dst = VbT + ((size_t)(b * NKVH + kvh) * HDIM + d) * SLEN + st * 64 + sc;
    *(bf16x8*)dst       = *(bf16x8*)&tmp[0];
    *(bf16x8*)(dst + 8) = *(bf16x8*)&tmp[8];
  }
}

// ---------------- Flash attention (unchanged) -------------------------------
__global__ __launch_bounds__(256) void attn_kernel(
    const bf16_t* Q, const bf16_t* __restrict__ Kg,
    const bf16_t* __restrict__ VT, bf16_t* O)
{
  const int pid = blockIdx.x;        // 0..7
  const int h   = blockIdx.y;
  const int b   = blockIdx.z;
  const int kvh = h >> 2;

  const int tid  = threadIdx.x;
  const int lane = tid & 63;
  const int w    = tid >> 6;
  const int fr   = lane & 15;
  const int quad = lane >> 4;

  const int PS  = 72;
  const int VTS = 136;
  __shared__ __align__(16) bf16_t KL[8192];
  __shared__ __align__(16) bf16_t PP[128 * 72];
  __shared__ __align__(16) bf16_t Vt[64 * 136];

  const size_t qbase = (size_t)b * SLEN;
  const bf16_t* VTh = VT + (size_t)(b * NKVH + kvh) * HDIM * SLEN;

  bf16x8 ones8;
  {
    const bf16_t o1 = (bf16_t)(fr == 0 ? 1.0f : 0.0f);
    for (int j = 0; j < 8; ++j) ones8[j] = o1;
  }

  for (int half = 0; half < 2; ++half) {
    const int qt = half ? (15 - pid) : pid;
    const int q0 = qt * 128;

    bf16x8 qf[2][2];
    for (int qi = 0; qi < 2; ++qi)
      for (int ks = 0; ks < 2; ++ks) {
        const size_t qrow = qbase + q0 + w * 32 + qi * 16 + fr;
        qf[qi][ks] = *(const bf16x8*)&Q[qrow * HID + h * HDIM + ks * 32 + quad * 8];
      }

    const f32x4 z4 = {0.f, 0.f, 0.f, 0.f};
    f32x4 o_acc[2][4];
    f32x4 o_l[2];
    for (int qi = 0; qi < 2; ++qi) {
      o_l[qi] = z4;
      for (int di = 0; di < 4; ++di) o_acc[qi][di] = z4;
    }

    for (int kt = 0; kt <= qt; ++kt) {
      const size_t krow0 = qbase + kt * 128;

      for (int t = 0; t < 4; ++t) {
        const int c  = w * 4 + t;
        const int hf = c >> 3;
        const int r  = (c & 7) * 16 + (lane >> 2);
        const int dk = hf * 32 + (lane & 3) * 8;
        gl2lds16(&Kg[(krow0 + r) * KVW + kvh * HDIM + dk], &KL[c * 512 + lane * 8]);
      }
      {
        const int d  = tid >> 2;
        const int kc = (tid & 3) * 32;
        const bf16_t* src = VTh + (size_t)d * SLEN + kt * 128 + kc;
        bf16x8 v0 = *(const bf16x8*)(src);
        bf16x8 v1 = *(const bf16x8*)(src + 8);
        bf16x8 v2 = *(const bf16x8*)(src + 16);
        bf16x8 v3 = *(const bf16x8*)(src + 24);
        bf16_t* dst = &Vt[d * VTS + kc];
        *(bf16x8*)(dst)      = v0;
        *(bf16x8*)(dst + 8)  = v1;
        *(bf16x8*)(dst + 16) = v2;
        *(bf16x8*)(dst + 24) = v3;
      }
      __syncthreads();

      f32x4 s[2][8];
      for (int qi = 0; qi < 2; ++qi)
        for (int ki = 0; ki < 8; ++ki) s[qi][ki] = z4;
      for (int ks = 0; ks < 2; ++ks)
        for (int ki = 0; ki < 8; ++ki) {
          bf16x8 kf = *(const bf16x8*)&KL[ks * 4096 + (ki * 16 + fr) * 32 + quad * 8];
          s[0][ki] = mfma16(qf[0][ks], kf, s[0][ki]);
          s[1][ki] = mfma16(qf[1][ks], kf, s[1][ki]);
        }

      const float C2 = 0.18033688f;   // log2(e)/8
      const bool diag = (kt == qt);
      for (int hk = 0; hk < 2; ++hk) {
        for (int qi = 0; qi < 2; ++qi)
          for (int k2 = 0; k2 < 4; ++k2) {
            const int ki = hk * 4 + k2;
            for (int r = 0; r < 4; ++r) {
              float pe = fast_exp2(s[qi][ki][r] * C2);
              if (diag && (ki * 16 + fr > w * 32 + qi * 16 + quad * 4 + r))
                pe = 0.f;
              PP[(w * 32 + qi * 16 + quad * 4 + r) * PS + k2 * 16 + fr] =
                  (bf16_t)pe;
            }
          }
        for (int k2 = 0; k2 < 2; ++k2) {
          bf16x8 pf0 = *(const bf16x8*)&PP[(w * 32 + fr) * PS + k2 * 32 + quad * 8];
          bf16x8 pf1 = *(const bf16x8*)&PP[(w * 32 + 16 + fr) * PS + k2 * 32 + quad * 8];
          o_l[0] = mfma16(pf0, ones8, o_l[0]);
          o_l[1] = mfma16(pf1, ones8, o_l[1]);
          const int kb = hk * 64 + k2 * 32;
          for (int di = 0; di < 4; ++di) {
            bf16x8 vf = *(const bf16x8*)&Vt[(di * 16 + fr) * VTS + kb + quad * 8];
            o_acc[0][di] = mfma16(pf0, vf, o_acc[0][di]);
            o_acc[1][di] = mfma16(pf1, vf, o_acc[1][di]);
          }
        }
      }
      __syncthreads();
    }

    for (int qi = 0; qi < 2; ++qi)
      for (int r = 0; r < 4; ++r) {
        const float l  = __shfl(o_l[qi][r], lane & 48);
        const float rl = 1.f / l;
        const size_t qg_ = qbase + q0 + w * 32 + qi * 16 + quad * 4 + r;
        for (int di = 0; di < 4; ++di)
          O[qg_ * HID + h * HDIM + di * 16 + fr] = (bf16_t)(o_acc[qi][di][r] * rl);
      }
  }
}

extern "C" void kernel_launch(void* const* d_in, const int* in_sizes, int n_in,
                              void* d_out, int out_size, void* d_ws, size_t ws_size,
                              hipStream_t stream) {
  const float* x  = (const float*)d_in[0];
  // d_in[1] = causal mask (int32) -- recomputed inline, not read
  const float* Wq = (const float*)d_in[2];
  const float* bq = (const float*)d_in[3];
  const float* Wk = (const float*)d_in[4];
  const float* bk = (const float*)d_in[5];
  const float* Wv = (const float*)d_in[6];
  const float* bv = (const float*)d_in[7];
  const float* Wo = (const float*)d_in[8];
  const float* bo = (const float*)d_in[9];
  float* out = (float*)d_out;

  const size_t M = (size_t)NB * SLEN;          // 4096
  dim3 blk(256, 1, 1);

  const size_t needA = (M * HID
                        + (size_t)HID * HID
                        + (size_t)KVW * HID
                        + (size_t)KVW * HID
                        + (size_t)HID * HID
                        + M * HID
                        + M * KVW
                        + M * KVW) * 2;
  if (ws_size >= needA) {
    bf16_t* xb  = (bf16_t*)d_ws;
    bf16_t* Wqb = xb  + M * HID;
    bf16_t* Wkb = Wqb + (size_t)HID * HID;
    bf16_t* Wvb = Wkb + (size_t)KVW * HID;
    bf16_t* Wob = Wvb + (size_t)KVW * HID;
    bf16_t* Qb  = Wob + (size_t)HID * HID;
    bf16_t* Kb  = Qb  + M * HID;
    bf16_t* VbT = Kb  + M * KVW;

    cvt_kernel<<<dim3(1024, 5, 1), blk, 0, stream>>>(
        x, Wq, Wk, Wv, Wo, xb, Wqb, Wkb, Wvb, Wob);
    qkv_dma_kernel<<<dim3(24, 32, 1), blk, 0, stream>>>(
        xb, Wqb, bq, Wkb, bk, Wvb, bv, Qb, Kb, VbT);
    attn_kernel<<<dim3(8, 32, 2), blk, 0, stream>>>(Qb, Kb, VbT, Qb);
    oproj_dma_kernel<<<dim3(16, 32, 1), blk, 0, stream>>>(Qb, Wob, bo, out);
  } else {
    bf16_t* Qb  = (bf16_t*)d_ws;
    bf16_t* Kb  = Qb + M * HID;
    bf16_t* Vb  = Kb + M * KVW;
    bf16_t* VbT = Vb + M * KVW;

    qkv_kernel<<<dim3(24, 32, 1), blk, 0, stream>>>(x, Wq, bq, Wk, bk, Wv, bv, Qb, Kb, Vb);
    vtrans_kernel<<<dim3(32, 8, 2), blk, 0, stream>>>(Vb, VbT);
    attn_kernel<<<dim3(8, 32, 2), blk, 0, stream>>>(Qb, Kb, VbT, Qb);
    oproj_kernel<<<dim3(16, 32, 1), blk, 0, stream>>>(Qb, Wo, bo, out);
  }
}